// Round 1
// baseline (504.713 us; speedup 1.0000x reference)
//
#include <hip/hip_runtime.h>
#include <math.h>

#define N_NODES 20000
#define N_EDGES 320000
#define NODE_DIM 256
#define HID 64
#define HEADS 4
#define OUTC 50
#define NEG_SLOPE 0.2f
#define BN_EPS 1e-5f

// ---------------- GEMM: C[M,Nc] = A[M,K] @ B[K,Nc], f32 ----------------
// BM=64, BN=64, BK=16, 256 threads, 4x4 per thread.
__global__ void gemm_f32_kernel(const float* __restrict__ A,
                                const float* __restrict__ B,
                                float* __restrict__ C,
                                int M, int K, int Ncols) {
  const int BM = 64, BN = 64, BK = 16;
  __shared__ float As[BK][BM + 4];
  __shared__ float Bs[BK][BN + 4];
  int bm = blockIdx.y * BM;
  int bn = blockIdx.x * BN;
  int tid = threadIdx.x;
  int tx = tid % 16, ty = tid / 16;

  float acc[4][4] = {};

  for (int k0 = 0; k0 < K; k0 += BK) {
    // load A tile: 64 rows x 16 k
    for (int i = tid; i < BM * BK; i += 256) {
      int r = i / BK, c = i % BK;
      float v = 0.f;
      if (bm + r < M) v = A[(size_t)(bm + r) * K + (k0 + c)];
      As[c][r] = v;
    }
    // load B tile: 16 k x 64 cols
    for (int i = tid; i < BK * BN; i += 256) {
      int r = i / BN, c = i % BN;
      Bs[r][c] = B[(size_t)(k0 + r) * Ncols + (bn + c)];
    }
    __syncthreads();
#pragma unroll
    for (int kk = 0; kk < BK; kk++) {
      float a[4], b[4];
#pragma unroll
      for (int i = 0; i < 4; i++) a[i] = As[kk][ty * 4 + i];
#pragma unroll
      for (int j = 0; j < 4; j++) b[j] = Bs[kk][tx * 4 + j];
#pragma unroll
      for (int i = 0; i < 4; i++)
#pragma unroll
        for (int j = 0; j < 4; j++) acc[i][j] += a[i] * b[j];
    }
    __syncthreads();
  }

  for (int i = 0; i < 4; i++) {
    int r = bm + ty * 4 + i;
    if (r < M) {
      for (int j = 0; j < 4; j++)
        C[(size_t)r * Ncols + (bn + tx * 4 + j)] = acc[i][j];
    }
  }
}

// ---------------- CSR build ----------------
__global__ void hist_kernel(const int* __restrict__ dst, int* __restrict__ deg) {
  int i = blockIdx.x * blockDim.x + threadIdx.x;
  if (i < N_EDGES) atomicAdd(&deg[dst[i]], 1);
}

__global__ void scan_kernel(const int* __restrict__ deg, int* __restrict__ rowptr) {
  // exclusive scan of deg[0..N) into rowptr[0..N], rowptr[N]=total. 1 block x 1024.
  __shared__ int part[1024];
  int tid = threadIdx.x;
  const int CH = (N_NODES + 1023) / 1024;  // 20
  int base = tid * CH;
  int s = 0;
  for (int i = 0; i < CH; i++) {
    int idx = base + i;
    if (idx < N_NODES) s += deg[idx];
  }
  part[tid] = s;
  __syncthreads();
  for (int off = 1; off < 1024; off <<= 1) {
    int v = (tid >= off) ? part[tid - off] : 0;
    __syncthreads();
    part[tid] += v;
    __syncthreads();
  }
  int run = (tid == 0) ? 0 : part[tid - 1];
  for (int i = 0; i < CH; i++) {
    int idx = base + i;
    if (idx < N_NODES) {
      rowptr[idx] = run;
      run += deg[idx];
    }
  }
  if (tid == 1023) rowptr[N_NODES] = run;
}

__global__ void scatter_kernel(const int* __restrict__ src, const int* __restrict__ dst,
                               const int* __restrict__ rowptr, int* __restrict__ cursor,
                               int* __restrict__ csr_src) {
  int i = blockIdx.x * blockDim.x + threadIdx.x;
  if (i < N_EDGES) {
    int d = dst[i];
    int pos = rowptr[d] + atomicAdd(&cursor[d], 1);
    csr_src[pos] = src[i];
  }
}

// ---------------- GATv2 aggregation, layer 1 (4 heads x 64) ----------------
// one wave per node; lane = dim within head; online softmax over incoming edges
__global__ void agg1_kernel(const float* __restrict__ xl, const float* __restrict__ xr,
                            const float* __restrict__ att, const float* __restrict__ bias,
                            const int* __restrict__ rowptr, const int* __restrict__ csr_src,
                            float* __restrict__ out) {
  int wave = threadIdx.x >> 6;
  int lane = threadIdx.x & 63;
  int n = blockIdx.x * 4 + wave;
  if (n >= N_NODES) return;

  float xi[HEADS], attr[HEADS], acc[HEADS], m[HEADS], l[HEADS];
#pragma unroll
  for (int h = 0; h < HEADS; h++) {
    xi[h] = xr[(size_t)n * 256 + h * 64 + lane];
    attr[h] = att[h * 64 + lane];
    acc[h] = 0.f;
    l[h] = 0.f;
    m[h] = -INFINITY;
  }
  int e0 = rowptr[n], e1 = rowptr[n + 1];
  for (int e = e0; e < e1; e++) {
    int s = csr_src[e];
    float xj[HEADS], t[HEADS];
#pragma unroll
    for (int h = 0; h < HEADS; h++) {
      xj[h] = xl[(size_t)s * 256 + h * 64 + lane];
      float u = xi[h] + xj[h];
      u = (u > 0.f) ? u : NEG_SLOPE * u;
      t[h] = u * attr[h];
    }
#pragma unroll
    for (int h = 0; h < HEADS; h++) {
      float v = t[h];
      for (int off = 32; off; off >>= 1) v += __shfl_xor(v, off);
      t[h] = v;
    }
#pragma unroll
    for (int h = 0; h < HEADS; h++) {
      float sc = t[h];
      float mn = fmaxf(m[h], sc);
      float rs = expf(m[h] - mn);
      float p = expf(sc - mn);
      acc[h] = acc[h] * rs + p * xj[h];
      l[h] = l[h] * rs + p;
      m[h] = mn;
    }
  }
#pragma unroll
  for (int h = 0; h < HEADS; h++) {
    out[(size_t)n * 256 + h * 64 + lane] = acc[h] / (l[h] + 1e-16f) + bias[h * 64 + lane];
  }
}

// ---------------- GATv2 aggregation, layer 2 (1 head x 64) ----------------
__global__ void agg2_kernel(const float* __restrict__ xl, const float* __restrict__ xr,
                            const float* __restrict__ att, const float* __restrict__ bias,
                            const int* __restrict__ rowptr, const int* __restrict__ csr_src,
                            float* __restrict__ out) {
  int wave = threadIdx.x >> 6;
  int lane = threadIdx.x & 63;
  int n = blockIdx.x * 4 + wave;
  if (n >= N_NODES) return;

  float xi = xr[(size_t)n * 64 + lane];
  float attr = att[lane];
  float acc = 0.f, l = 0.f, m = -INFINITY;
  int e0 = rowptr[n], e1 = rowptr[n + 1];
  for (int e = e0; e < e1; e++) {
    int s = csr_src[e];
    float xj = xl[(size_t)s * 64 + lane];
    float u = xi + xj;
    u = (u > 0.f) ? u : NEG_SLOPE * u;
    float v = u * attr;
    for (int off = 32; off; off >>= 1) v += __shfl_xor(v, off);
    float mn = fmaxf(m, v);
    float rs = expf(m - mn);
    float p = expf(v - mn);
    acc = acc * rs + p * xj;
    l = l * rs + p;
    m = mn;
  }
  out[(size_t)n * 64 + lane] = acc / (l + 1e-16f) + bias[lane];
}

// ---------------- BatchNorm reduce: per-channel sum & sumsq ----------------
__global__ void bn_reduce_kernel(const float* __restrict__ x, float* __restrict__ sums,
                                 int C, int rowsPerBlock) {
  int tid = threadIdx.x;
  int c = tid % C;
  int rstep = blockDim.x / C;
  int r0 = blockIdx.x * rowsPerBlock + tid / C;
  int r1 = min(blockIdx.x * rowsPerBlock + rowsPerBlock, N_NODES);
  float s = 0.f, q = 0.f;
  for (int r = r0; r < r1; r += rstep) {
    float v = x[(size_t)r * C + c];
    s += v;
    q += v * v;
  }
  atomicAdd(&sums[c], s);
  atomicAdd(&sums[C + c], q);
}

// ---------------- BN finalize + exact GELU, in-place capable ----------------
__global__ void bn_gelu_kernel(const float* __restrict__ x, const float* __restrict__ sums,
                               const float* __restrict__ g, const float* __restrict__ b,
                               float* __restrict__ y, int C) {
  size_t total = (size_t)N_NODES * C;
  for (size_t i = blockIdx.x * (size_t)blockDim.x + threadIdx.x; i < total;
       i += (size_t)gridDim.x * blockDim.x) {
    int c = (int)(i % C);
    float mu = sums[c] * (1.0f / N_NODES);
    float var = sums[C + c] * (1.0f / N_NODES) - mu * mu;
    float v = (x[i] - mu) * rsqrtf(var + BN_EPS) * g[c] + b[c];
    y[i] = 0.5f * v * (1.f + erff(v * 0.70710678118f));
  }
}

// ---------------- classifier head + log_softmax ----------------
__global__ void head_kernel(const float* __restrict__ h, const float* __restrict__ Wc,
                            const float* __restrict__ bc, float* __restrict__ out) {
  __shared__ float Ws[HID * OUTC];
  __shared__ float bs[OUTC];
  for (int i = threadIdx.x; i < HID * OUTC; i += 256) Ws[i] = Wc[i];
  for (int i = threadIdx.x; i < OUTC; i += 256) bs[i] = bc[i];
  __syncthreads();

  int wave = threadIdx.x >> 6;
  int lane = threadIdx.x & 63;
  int n = blockIdx.x * 4 + wave;
  if (n >= N_NODES) return;

  float hrow = h[(size_t)n * HID + lane];
  float dot = 0.f;
#pragma unroll
  for (int k = 0; k < HID; k++) {
    float hk = __shfl(hrow, k);
    if (lane < OUTC) dot += hk * Ws[k * OUTC + lane];
  }
  float z = (lane < OUTC) ? (dot + bs[lane]) : -INFINITY;
  float mv = z;
  for (int off = 32; off; off >>= 1) mv = fmaxf(mv, __shfl_xor(mv, off));
  float p = (lane < OUTC) ? expf(z - mv) : 0.f;
  float sum = p;
  for (int off = 32; off; off >>= 1) sum += __shfl_xor(sum, off);
  if (lane < OUTC) out[(size_t)n * OUTC + lane] = z - mv - logf(sum);
}

// ---------------- launch ----------------
extern "C" void kernel_launch(void* const* d_in, const int* in_sizes, int n_in,
                              void* d_out, int out_size, void* d_ws, size_t ws_size,
                              hipStream_t stream) {
  const float* x = (const float*)d_in[0];
  const int* eidx = (const int*)d_in[1];
  const float* W1l = (const float*)d_in[2];
  const float* W1r = (const float*)d_in[3];
  const float* att1 = (const float*)d_in[4];
  const float* b1 = (const float*)d_in[5];
  const float* bn1_g = (const float*)d_in[6];
  const float* bn1_b = (const float*)d_in[7];
  const float* W2l = (const float*)d_in[8];
  const float* W2r = (const float*)d_in[9];
  const float* att2 = (const float*)d_in[10];
  const float* b2 = (const float*)d_in[11];
  const float* bn2_g = (const float*)d_in[12];
  const float* bn2_b = (const float*)d_in[13];
  const float* Wc = (const float*)d_in[14];
  const float* bc = (const float*)d_in[15];
  float* out = (float*)d_out;

  const int* src = eidx;            // edge_index[0]
  const int* dstv = eidx + N_EDGES; // edge_index[1]

  char* ws = (char*)d_ws;
  // workspace layout (bytes)
  float* xl1 = (float*)(ws + 0);            // 20,480,000
  float* xr1 = (float*)(ws + 20480000);     // 20,480,000
  float* out1 = (float*)(ws + 40960000);    // 20,480,000  (becomes h1 in-place)
  float* out2 = (float*)(ws + 61440000);    //  5,120,000  (becomes h2 in-place)
  float* xl2 = (float*)(ws + 66560000);     //  5,120,000
  float* xr2 = (float*)(ws + 71680000);     //  5,120,000
  // zeroed-every-call region: deg, cursor, bnsum1(512f), bnsum2(128f)
  int* deg = (int*)(ws + 76800000);         // 80,000
  int* cursor = (int*)(ws + 76880000);      // 80,000
  float* bnsum1 = (float*)(ws + 76960000);  // 2,048
  float* bnsum2 = (float*)(ws + 76962048);  // 512
  int* rowptr = (int*)(ws + 76962560);      // 80,016
  int* csr_src = (int*)(ws + 77042576);     // 1,280,000

  hipMemsetAsync(ws + 76800000, 0, 162560, stream);

  // layer-1 transforms
  {
    dim3 grid(NODE_DIM / 64, (N_NODES + 63) / 64);
    gemm_f32_kernel<<<grid, 256, 0, stream>>>(x, W1l, xl1, N_NODES, NODE_DIM, HEADS * HID);
    gemm_f32_kernel<<<grid, 256, 0, stream>>>(x, W1r, xr1, N_NODES, NODE_DIM, HEADS * HID);
  }

  // CSR build
  hist_kernel<<<(N_EDGES + 255) / 256, 256, 0, stream>>>(dstv, deg);
  scan_kernel<<<1, 1024, 0, stream>>>(deg, rowptr);
  scatter_kernel<<<(N_EDGES + 255) / 256, 256, 0, stream>>>(src, dstv, rowptr, cursor, csr_src);

  // layer-1 attention aggregation (+bias)
  agg1_kernel<<<N_NODES / 4, 256, 0, stream>>>(xl1, xr1, att1, b1, rowptr, csr_src, out1);

  // BN1 + GELU (in place)
  bn_reduce_kernel<<<N_NODES / 100, 256, 0, stream>>>(out1, bnsum1, 256, 100);
  bn_gelu_kernel<<<2048, 256, 0, stream>>>(out1, bnsum1, bn1_g, bn1_b, out1, 256);

  // layer-2 transforms
  {
    dim3 grid(HID / 64, (N_NODES + 63) / 64);
    gemm_f32_kernel<<<grid, 256, 0, stream>>>(out1, W2l, xl2, N_NODES, HEADS * HID, HID);
    gemm_f32_kernel<<<grid, 256, 0, stream>>>(out1, W2r, xr2, N_NODES, HEADS * HID, HID);
  }

  // layer-2 attention aggregation (+bias)
  agg2_kernel<<<N_NODES / 4, 256, 0, stream>>>(xl2, xr2, att2, b2, rowptr, csr_src, out2);

  // BN2 + GELU (in place)
  bn_reduce_kernel<<<N_NODES / 100, 256, 0, stream>>>(out2, bnsum2, 64, 100);
  bn_gelu_kernel<<<2048, 256, 0, stream>>>(out2, bnsum2, bn2_g, bn2_b, out2, 64);

  // classifier + log_softmax
  head_kernel<<<N_NODES / 4, 256, 0, stream>>>(out2, Wc, bc, out);
}

// Round 2
// 501.277 us; speedup vs baseline: 1.0069x; 1.0069x over previous
//
#include <hip/hip_runtime.h>
#include <math.h>

#define N_NODES 20000
#define N_EDGES 320000
#define NODE_DIM 256
#define HID 64
#define HEADS 4
#define OUTC 50
#define NEG_SLOPE 0.2f
#define BN_EPS 1e-5f

// ---------------- Dual GEMM: C0 = A@B0, C1 = A@B1 (shared A tile) ----------------
// BM=64, BN=64, BK=16, 256 threads, 4x4 per thread per output.
// TOUT: store in transposed-head layout  idx = r*256 + (c&63)*4 + (c>>6)
template <bool TOUT>
__global__ void gemm_dual_kernel(const float* __restrict__ A,
                                 const float* __restrict__ B0,
                                 const float* __restrict__ B1,
                                 float* __restrict__ C0,
                                 float* __restrict__ C1,
                                 int M, int K, int Ncols) {
  const int BM = 64, BN = 64, BK = 16;
  __shared__ float As[BK][BM + 4];
  __shared__ float B0s[BK][BN + 4];
  __shared__ float B1s[BK][BN + 4];
  int bm = blockIdx.y * BM;
  int bn = blockIdx.x * BN;
  int tid = threadIdx.x;
  int tx = tid % 16, ty = tid / 16;

  float acc0[4][4] = {};
  float acc1[4][4] = {};

  for (int k0 = 0; k0 < K; k0 += BK) {
    for (int i = tid; i < BM * BK; i += 256) {
      int r = i / BK, c = i % BK;
      float v = 0.f;
      if (bm + r < M) v = A[(size_t)(bm + r) * K + (k0 + c)];
      As[c][r] = v;
    }
    for (int i = tid; i < BK * BN; i += 256) {
      int r = i / BN, c = i % BN;
      B0s[r][c] = B0[(size_t)(k0 + r) * Ncols + (bn + c)];
      B1s[r][c] = B1[(size_t)(k0 + r) * Ncols + (bn + c)];
    }
    __syncthreads();
#pragma unroll
    for (int kk = 0; kk < BK; kk++) {
      float a[4], b0[4], b1[4];
#pragma unroll
      for (int i = 0; i < 4; i++) a[i] = As[kk][ty * 4 + i];
#pragma unroll
      for (int j = 0; j < 4; j++) {
        b0[j] = B0s[kk][tx * 4 + j];
        b1[j] = B1s[kk][tx * 4 + j];
      }
#pragma unroll
      for (int i = 0; i < 4; i++)
#pragma unroll
        for (int j = 0; j < 4; j++) {
          acc0[i][j] += a[i] * b0[j];
          acc1[i][j] += a[i] * b1[j];
        }
    }
    __syncthreads();
  }

  for (int i = 0; i < 4; i++) {
    int r = bm + ty * 4 + i;
    if (r < M) {
      for (int j = 0; j < 4; j++) {
        int c = bn + tx * 4 + j;
        size_t idx;
        if (TOUT)
          idx = (size_t)r * 256 + (size_t)(c & 63) * 4 + (c >> 6);
        else
          idx = (size_t)r * Ncols + c;
        C0[idx] = acc0[i][j];
        C1[idx] = acc1[i][j];
      }
    }
  }
}

// ---------------- CSR build ----------------
__global__ void hist_kernel(const int* __restrict__ dst, int* __restrict__ deg) {
  int i = blockIdx.x * blockDim.x + threadIdx.x;
  if (i < N_EDGES) atomicAdd(&deg[dst[i]], 1);
}

__global__ void scan_kernel(const int* __restrict__ deg, int* __restrict__ rowptr) {
  __shared__ int part[1024];
  int tid = threadIdx.x;
  const int CH = (N_NODES + 1023) / 1024;  // 20
  int base = tid * CH;
  int s = 0;
  for (int i = 0; i < CH; i++) {
    int idx = base + i;
    if (idx < N_NODES) s += deg[idx];
  }
  part[tid] = s;
  __syncthreads();
  for (int off = 1; off < 1024; off <<= 1) {
    int v = (tid >= off) ? part[tid - off] : 0;
    __syncthreads();
    part[tid] += v;
    __syncthreads();
  }
  int run = (tid == 0) ? 0 : part[tid - 1];
  for (int i = 0; i < CH; i++) {
    int idx = base + i;
    if (idx < N_NODES) {
      rowptr[idx] = run;
      run += deg[idx];
    }
  }
  if (tid == 1023) rowptr[N_NODES] = run;
}

__global__ void scatter_kernel(const int* __restrict__ src, const int* __restrict__ dst,
                               const int* __restrict__ rowptr, int* __restrict__ cursor,
                               int* __restrict__ csr_src) {
  int i = blockIdx.x * blockDim.x + threadIdx.x;
  if (i < N_EDGES) {
    int d = dst[i];
    int pos = rowptr[d] + atomicAdd(&cursor[d], 1);
    csr_src[pos] = src[i];
  }
}

// ---------------- GATv2 aggregation, layer 1 (4 heads x 64) ----------------
// one wave per node; lane = dim; xl/xr in [n][d][h] float4 layout.
// No-max softmax (scores are O(1); exp is shift-invariant-safe in f32).
__global__ void agg1_kernel(const float4* __restrict__ xl, const float4* __restrict__ xr,
                            const float* __restrict__ att, const float* __restrict__ bias,
                            const int* __restrict__ rowptr, const int* __restrict__ csr_src,
                            float* __restrict__ out) {
  int wave = threadIdx.x >> 6;
  int lane = threadIdx.x & 63;
  int n = blockIdx.x * 4 + wave;
  if (n >= N_NODES) return;

  float4 xi = xr[(size_t)n * 64 + lane];
  float attr0 = att[0 * 64 + lane];
  float attr1 = att[1 * 64 + lane];
  float attr2 = att[2 * 64 + lane];
  float attr3 = att[3 * 64 + lane];

  float acc0 = 0.f, acc1 = 0.f, acc2 = 0.f, acc3 = 0.f;
  float lsum = 0.f;  // per-16-lane-group: l for head (lane>>4)

  const bool hi32 = (lane & 32) != 0;
  const bool hi16 = (lane & 16) != 0;

  int e0 = rowptr[n], e1 = rowptr[n + 1];
  for (int e = e0; e < e1; e++) {
    int s = csr_src[e];
    float4 xj = xl[(size_t)s * 64 + lane];

    float u0 = xi.x + xj.x, u1 = xi.y + xj.y, u2 = xi.z + xj.z, u3 = xi.w + xj.w;
    float t0 = fmaxf(u0, NEG_SLOPE * u0) * attr0;
    float t1 = fmaxf(u1, NEG_SLOPE * u1) * attr1;
    float t2 = fmaxf(u2, NEG_SLOPE * u2) * attr2;
    float t3 = fmaxf(u3, NEG_SLOPE * u3) * attr3;

    // fold 4 independent 64-lane sums into 4 x 16-lane groups (7 shuffles)
    float w0 = hi32 ? t2 : t0, y0 = hi32 ? t0 : t2;
    float w1 = hi32 ? t3 : t1, y1 = hi32 ? t1 : t3;
    w0 += __shfl_xor(y0, 32);
    w1 += __shfl_xor(y1, 32);
    float a = hi16 ? w1 : w0, b = hi16 ? w0 : w1;
    a += __shfl_xor(b, 16);
    a += __shfl_xor(a, 8);
    a += __shfl_xor(a, 4);
    a += __shfl_xor(a, 2);
    a += __shfl_xor(a, 1);
    // group g = lane>>4 now holds score of head g

    float ev = expf(a);
    lsum += ev;

    float p0 = __shfl(ev, 0);
    float p1 = __shfl(ev, 16);
    float p2 = __shfl(ev, 32);
    float p3 = __shfl(ev, 48);
    acc0 += p0 * xj.x;
    acc1 += p1 * xj.y;
    acc2 += p2 * xj.z;
    acc3 += p3 * xj.w;
  }

  float l0 = __shfl(lsum, 0) + 1e-16f;
  float l1 = __shfl(lsum, 16) + 1e-16f;
  float l2 = __shfl(lsum, 32) + 1e-16f;
  float l3 = __shfl(lsum, 48) + 1e-16f;
  out[(size_t)n * 256 + 0 * 64 + lane] = acc0 / l0 + bias[0 * 64 + lane];
  out[(size_t)n * 256 + 1 * 64 + lane] = acc1 / l1 + bias[1 * 64 + lane];
  out[(size_t)n * 256 + 2 * 64 + lane] = acc2 / l2 + bias[2 * 64 + lane];
  out[(size_t)n * 256 + 3 * 64 + lane] = acc3 / l3 + bias[3 * 64 + lane];
}

// ---------------- GATv2 aggregation, layer 2 (1 head x 64) ----------------
__global__ void agg2_kernel(const float* __restrict__ xl, const float* __restrict__ xr,
                            const float* __restrict__ att, const float* __restrict__ bias,
                            const int* __restrict__ rowptr, const int* __restrict__ csr_src,
                            float* __restrict__ out) {
  int wave = threadIdx.x >> 6;
  int lane = threadIdx.x & 63;
  int n = blockIdx.x * 4 + wave;
  if (n >= N_NODES) return;

  float xi = xr[(size_t)n * 64 + lane];
  float attr = att[lane];
  float acc = 0.f, l = 0.f;
  int e0 = rowptr[n], e1 = rowptr[n + 1];
  for (int e = e0; e < e1; e++) {
    int s = csr_src[e];
    float xj = xl[(size_t)s * 64 + lane];
    float u = xi + xj;
    float v = fmaxf(u, NEG_SLOPE * u) * attr;
    v += __shfl_xor(v, 32);
    v += __shfl_xor(v, 16);
    v += __shfl_xor(v, 8);
    v += __shfl_xor(v, 4);
    v += __shfl_xor(v, 2);
    v += __shfl_xor(v, 1);
    float p = expf(v);
    acc += p * xj;
    l += p;
  }
  out[(size_t)n * 64 + lane] = acc / (l + 1e-16f) + bias[lane];
}

// ---------------- BatchNorm reduce: per-channel sum & sumsq ----------------
__global__ void bn_reduce_kernel(const float* __restrict__ x, float* __restrict__ sums,
                                 int C, int rowsPerBlock) {
  int tid = threadIdx.x;
  int c = tid % C;
  int rstep = blockDim.x / C;
  int r0 = blockIdx.x * rowsPerBlock + tid / C;
  int r1 = min(blockIdx.x * rowsPerBlock + rowsPerBlock, N_NODES);
  float s = 0.f, q = 0.f;
  for (int r = r0; r < r1; r += rstep) {
    float v = x[(size_t)r * C + c];
    s += v;
    q += v * v;
  }
  atomicAdd(&sums[c], s);
  atomicAdd(&sums[C + c], q);
}

// ---------------- BN finalize + exact GELU ----------------
__global__ void bn_gelu_kernel(const float* __restrict__ x, const float* __restrict__ sums,
                               const float* __restrict__ g, const float* __restrict__ b,
                               float* __restrict__ y, int C) {
  size_t total = (size_t)N_NODES * C;
  for (size_t i = blockIdx.x * (size_t)blockDim.x + threadIdx.x; i < total;
       i += (size_t)gridDim.x * blockDim.x) {
    int c = (int)(i % C);
    float mu = sums[c] * (1.0f / N_NODES);
    float var = sums[C + c] * (1.0f / N_NODES) - mu * mu;
    float v = (x[i] - mu) * rsqrtf(var + BN_EPS) * g[c] + b[c];
    y[i] = 0.5f * v * (1.f + erff(v * 0.70710678118f));
  }
}

// ---------------- classifier head + log_softmax ----------------
__global__ void head_kernel(const float* __restrict__ h, const float* __restrict__ Wc,
                            const float* __restrict__ bc, float* __restrict__ out) {
  __shared__ float Ws[HID * OUTC];
  __shared__ float bs[OUTC];
  for (int i = threadIdx.x; i < HID * OUTC; i += 256) Ws[i] = Wc[i];
  for (int i = threadIdx.x; i < OUTC; i += 256) bs[i] = bc[i];
  __syncthreads();

  int wave = threadIdx.x >> 6;
  int lane = threadIdx.x & 63;
  int n = blockIdx.x * 4 + wave;
  if (n >= N_NODES) return;

  float hrow = h[(size_t)n * HID + lane];
  float dot = 0.f;
#pragma unroll
  for (int k = 0; k < HID; k++) {
    float hk = __shfl(hrow, k);
    if (lane < OUTC) dot += hk * Ws[k * OUTC + lane];
  }
  float z = (lane < OUTC) ? (dot + bs[lane]) : -INFINITY;
  float mv = z;
  for (int off = 32; off; off >>= 1) mv = fmaxf(mv, __shfl_xor(mv, off));
  float p = (lane < OUTC) ? expf(z - mv) : 0.f;
  float sum = p;
  for (int off = 32; off; off >>= 1) sum += __shfl_xor(sum, off);
  if (lane < OUTC) out[(size_t)n * OUTC + lane] = z - mv - logf(sum);
}

// ---------------- launch ----------------
extern "C" void kernel_launch(void* const* d_in, const int* in_sizes, int n_in,
                              void* d_out, int out_size, void* d_ws, size_t ws_size,
                              hipStream_t stream) {
  const float* x = (const float*)d_in[0];
  const int* eidx = (const int*)d_in[1];
  const float* W1l = (const float*)d_in[2];
  const float* W1r = (const float*)d_in[3];
  const float* att1 = (const float*)d_in[4];
  const float* b1 = (const float*)d_in[5];
  const float* bn1_g = (const float*)d_in[6];
  const float* bn1_b = (const float*)d_in[7];
  const float* W2l = (const float*)d_in[8];
  const float* W2r = (const float*)d_in[9];
  const float* att2 = (const float*)d_in[10];
  const float* b2 = (const float*)d_in[11];
  const float* bn2_g = (const float*)d_in[12];
  const float* bn2_b = (const float*)d_in[13];
  const float* Wc = (const float*)d_in[14];
  const float* bc = (const float*)d_in[15];
  float* out = (float*)d_out;

  const int* src = eidx;
  const int* dstv = eidx + N_EDGES;

  char* ws = (char*)d_ws;
  float* xl1 = (float*)(ws + 0);            // transposed [n][d][h]
  float* xr1 = (float*)(ws + 20480000);     // transposed [n][d][h]
  float* out1 = (float*)(ws + 40960000);
  float* out2 = (float*)(ws + 61440000);
  float* xl2 = (float*)(ws + 66560000);
  float* xr2 = (float*)(ws + 71680000);
  int* deg = (int*)(ws + 76800000);
  int* cursor = (int*)(ws + 76880000);
  float* bnsum1 = (float*)(ws + 76960000);
  float* bnsum2 = (float*)(ws + 76962048);
  int* rowptr = (int*)(ws + 76962560);
  int* csr_src = (int*)(ws + 77042576);

  hipMemsetAsync(ws + 76800000, 0, 162560, stream);

  // layer-1 transforms (fused dual GEMM, transposed-head output layout)
  {
    dim3 grid(NODE_DIM / 64, (N_NODES + 63) / 64);
    gemm_dual_kernel<true><<<grid, 256, 0, stream>>>(x, W1l, W1r, xl1, xr1,
                                                     N_NODES, NODE_DIM, HEADS * HID);
  }

  // CSR build
  hist_kernel<<<(N_EDGES + 255) / 256, 256, 0, stream>>>(dstv, deg);
  scan_kernel<<<1, 1024, 0, stream>>>(deg, rowptr);
  scatter_kernel<<<(N_EDGES + 255) / 256, 256, 0, stream>>>(src, dstv, rowptr, cursor, csr_src);

  // layer-1 attention aggregation (+bias)
  agg1_kernel<<<N_NODES / 4, 256, 0, stream>>>((const float4*)xl1, (const float4*)xr1,
                                               att1, b1, rowptr, csr_src, out1);

  // BN1 + GELU (in place)
  bn_reduce_kernel<<<800, 256, 0, stream>>>(out1, bnsum1, 256, 25);
  bn_gelu_kernel<<<2048, 256, 0, stream>>>(out1, bnsum1, bn1_g, bn1_b, out1, 256);

  // layer-2 transforms (fused dual GEMM, standard layout)
  {
    dim3 grid(HID / 64, (N_NODES + 63) / 64);
    gemm_dual_kernel<false><<<grid, 256, 0, stream>>>(out1, W2l, W2r, xl2, xr2,
                                                      N_NODES, HEADS * HID, HID);
  }

  // layer-2 attention aggregation (+bias)
  agg2_kernel<<<N_NODES / 4, 256, 0, stream>>>(xl2, xr2, att2, b2, rowptr, csr_src, out2);

  // BN2 + GELU (in place)
  bn_reduce_kernel<<<800, 256, 0, stream>>>(out2, bnsum2, 64, 25);
  bn_gelu_kernel<<<2048, 256, 0, stream>>>(out2, bnsum2, bn2_g, bn2_b, out2, 64);

  // classifier + log_softmax
  head_kernel<<<N_NODES / 4, 256, 0, stream>>>(out2, Wc, bc, out);
}

// Round 3
// 419.751 us; speedup vs baseline: 1.2024x; 1.1942x over previous
//
#include <hip/hip_runtime.h>
#include <math.h>

#define N_NODES 20000
#define N_EDGES 320000
#define NODE_DIM 256
#define HID 64
#define HEADS 4
#define OUTC 50
#define NEG_SLOPE 0.2f
#define BN_EPS 1e-5f

typedef __attribute__((ext_vector_type(8))) short short8;
typedef __attribute__((ext_vector_type(8))) unsigned short ushort8;
typedef __attribute__((ext_vector_type(4))) unsigned short ushort4v;
typedef __attribute__((ext_vector_type(4))) float f32x4;

__device__ inline unsigned short f2bf(float f) {
  unsigned u = __float_as_uint(f);
  u += 0x7fffu + ((u >> 16) & 1u);
  return (unsigned short)(u >> 16);
}

// ---------------- casts ----------------
__global__ void cast_f32_bf16_kernel(const float* __restrict__ in,
                                     unsigned short* __restrict__ out, int n4) {
  int i = blockIdx.x * blockDim.x + threadIdx.x;
  if (i >= n4) return;
  float4 v = ((const float4*)in)[i];
  ushort4v o = {f2bf(v.x), f2bf(v.y), f2bf(v.z), f2bf(v.w)};
  ((ushort4v*)out)[i] = o;
}

__global__ void cast_weights_kernel(const float* __restrict__ a, const float* __restrict__ b,
                                    const float* __restrict__ c, const float* __restrict__ d,
                                    unsigned short* oa, unsigned short* ob,
                                    unsigned short* oc, unsigned short* od) {
  int i = blockIdx.x * blockDim.x + threadIdx.x;
  if (i < 65536) { oa[i] = f2bf(a[i]); ob[i] = f2bf(b[i]); }
  if (i < 16384) { oc[i] = f2bf(c[i]); od[i] = f2bf(d[i]); }
}

// ---------------- bf16 MFMA GEMM: C[M,N] = A[M,K] @ B[K,N] ----------------
// BM=128, BN=64, BK=32. 256 threads = 4 waves; wave w: rows [w*32, w*32+32).
// LDS row stride 40 ushorts (80B) -> ds_read_b128 lands 2-way bank alias (free).
__global__ __launch_bounds__(256) void gemm_bf16_kernel(
    const unsigned short* __restrict__ A, const unsigned short* __restrict__ B,
    float* __restrict__ C, int M, int K, int N) {
  __shared__ unsigned short As[128][40];
  __shared__ unsigned short Bs[64][40];
  int tid = threadIdx.x;
  int lane = tid & 63, w = tid >> 6;
  int bm = blockIdx.y * 128, bn = blockIdx.x * 64;

  f32x4 acc[2][4] = {};

  for (int k0 = 0; k0 < K; k0 += 32) {
    // A tile: 128 rows x 32 k (8KB), 512 16B-segments, 2 per thread
#pragma unroll
    for (int s = tid; s < 512; s += 256) {
      int row = s >> 2, half = s & 3;
      int gr = bm + row;
      ushort8 v = {0, 0, 0, 0, 0, 0, 0, 0};
      if (gr < M) v = *(const ushort8*)&A[(size_t)gr * K + k0 + half * 8];
      *(ushort8*)&As[row][half * 8] = v;
    }
    // B tile: 32 k x 64 n, stored transposed Bs[col][k]
    {
      int k = tid >> 3, c0 = (tid & 7) * 8;
      ushort8 v = *(const ushort8*)&B[(size_t)(k0 + k) * N + bn + c0];
#pragma unroll
      for (int j = 0; j < 8; j++) Bs[c0 + j][k] = v[j];
    }
    __syncthreads();

    short8 av[2], bv[4];
#pragma unroll
    for (int fr = 0; fr < 2; fr++)
      av[fr] = *(const short8*)&As[w * 32 + fr * 16 + (lane & 15)][(lane >> 4) * 8];
#pragma unroll
    for (int fc = 0; fc < 4; fc++)
      bv[fc] = *(const short8*)&Bs[fc * 16 + (lane & 15)][(lane >> 4) * 8];
#pragma unroll
    for (int fr = 0; fr < 2; fr++)
#pragma unroll
      for (int fc = 0; fc < 4; fc++)
        acc[fr][fc] = __builtin_amdgcn_mfma_f32_16x16x32_bf16(av[fr], bv[fc], acc[fr][fc], 0, 0, 0);
    __syncthreads();
  }

#pragma unroll
  for (int fr = 0; fr < 2; fr++)
#pragma unroll
    for (int fc = 0; fc < 4; fc++)
#pragma unroll
      for (int i = 0; i < 4; i++) {
        int r = bm + w * 32 + fr * 16 + (lane >> 4) * 4 + i;
        if (r < M) C[(size_t)r * N + bn + fc * 16 + (lane & 15)] = acc[fr][fc][i];
      }
}

// ---------------- head transpose: [n][h][d] x2 -> [n][d][h] float4 x2 ----------------
__global__ void transpose_heads_kernel(const float* __restrict__ C0, const float* __restrict__ C1,
                                       float4* __restrict__ X0, float4* __restrict__ X1) {
  int i = blockIdx.x * blockDim.x + threadIdx.x;  // over N_NODES*64
  if (i >= N_NODES * 64) return;
  int n = i >> 6, d = i & 63;
  const float* r0 = C0 + (size_t)n * 256;
  const float* r1 = C1 + (size_t)n * 256;
  X0[i] = make_float4(r0[d], r0[64 + d], r0[128 + d], r0[192 + d]);
  X1[i] = make_float4(r1[d], r1[64 + d], r1[128 + d], r1[192 + d]);
}

// ---------------- CSR build ----------------
__global__ void hist_kernel(const int* __restrict__ dst, int* __restrict__ deg) {
  int i = blockIdx.x * blockDim.x + threadIdx.x;
  if (i < N_EDGES) atomicAdd(&deg[dst[i]], 1);
}

__global__ void scan_kernel(const int* __restrict__ deg, int* __restrict__ rowptr) {
  __shared__ int part[1024];
  int tid = threadIdx.x;
  const int CH = (N_NODES + 1023) / 1024;  // 20
  int base = tid * CH;
  int s = 0;
  for (int i = 0; i < CH; i++) {
    int idx = base + i;
    if (idx < N_NODES) s += deg[idx];
  }
  part[tid] = s;
  __syncthreads();
  for (int off = 1; off < 1024; off <<= 1) {
    int v = (tid >= off) ? part[tid - off] : 0;
    __syncthreads();
    part[tid] += v;
    __syncthreads();
  }
  int run = (tid == 0) ? 0 : part[tid - 1];
  for (int i = 0; i < CH; i++) {
    int idx = base + i;
    if (idx < N_NODES) {
      rowptr[idx] = run;
      run += deg[idx];
    }
  }
  if (tid == 1023) rowptr[N_NODES] = run;
}

__global__ void scatter_kernel(const int* __restrict__ src, const int* __restrict__ dst,
                               const int* __restrict__ rowptr, int* __restrict__ cursor,
                               int* __restrict__ csr_src) {
  int i = blockIdx.x * blockDim.x + threadIdx.x;
  if (i < N_EDGES) {
    int d = dst[i];
    int pos = rowptr[d] + atomicAdd(&cursor[d], 1);
    csr_src[pos] = src[i];
  }
}

// ---------------- GATv2 aggregation, layer 1 (4 heads x 64) ----------------
__global__ void agg1_kernel(const float4* __restrict__ xl, const float4* __restrict__ xr,
                            const float* __restrict__ att, const float* __restrict__ bias,
                            const int* __restrict__ rowptr, const int* __restrict__ csr_src,
                            float* __restrict__ out) {
  int wave = threadIdx.x >> 6;
  int lane = threadIdx.x & 63;
  int n = blockIdx.x * 4 + wave;
  if (n >= N_NODES) return;

  float4 xi = xr[(size_t)n * 64 + lane];
  float attr0 = att[0 * 64 + lane];
  float attr1 = att[1 * 64 + lane];
  float attr2 = att[2 * 64 + lane];
  float attr3 = att[3 * 64 + lane];

  float acc0 = 0.f, acc1 = 0.f, acc2 = 0.f, acc3 = 0.f;
  float lsum = 0.f;

  const bool hi32 = (lane & 32) != 0;
  const bool hi16 = (lane & 16) != 0;

  int e0 = rowptr[n], e1 = rowptr[n + 1];
  for (int e = e0; e < e1; e++) {
    int s = csr_src[e];
    float4 xj = xl[(size_t)s * 64 + lane];

    float u0 = xi.x + xj.x, u1 = xi.y + xj.y, u2 = xi.z + xj.z, u3 = xi.w + xj.w;
    float t0 = fmaxf(u0, NEG_SLOPE * u0) * attr0;
    float t1 = fmaxf(u1, NEG_SLOPE * u1) * attr1;
    float t2 = fmaxf(u2, NEG_SLOPE * u2) * attr2;
    float t3 = fmaxf(u3, NEG_SLOPE * u3) * attr3;

    float w0 = hi32 ? t2 : t0, y0 = hi32 ? t0 : t2;
    float w1 = hi32 ? t3 : t1, y1 = hi32 ? t1 : t3;
    w0 += __shfl_xor(y0, 32);
    w1 += __shfl_xor(y1, 32);
    float a = hi16 ? w1 : w0, b = hi16 ? w0 : w1;
    a += __shfl_xor(b, 16);
    a += __shfl_xor(a, 8);
    a += __shfl_xor(a, 4);
    a += __shfl_xor(a, 2);
    a += __shfl_xor(a, 1);

    float ev = expf(a);
    lsum += ev;

    float p0 = __shfl(ev, 0);
    float p1 = __shfl(ev, 16);
    float p2 = __shfl(ev, 32);
    float p3 = __shfl(ev, 48);
    acc0 += p0 * xj.x;
    acc1 += p1 * xj.y;
    acc2 += p2 * xj.z;
    acc3 += p3 * xj.w;
  }

  float l0 = __shfl(lsum, 0) + 1e-16f;
  float l1 = __shfl(lsum, 16) + 1e-16f;
  float l2 = __shfl(lsum, 32) + 1e-16f;
  float l3 = __shfl(lsum, 48) + 1e-16f;
  out[(size_t)n * 256 + 0 * 64 + lane] = acc0 / l0 + bias[0 * 64 + lane];
  out[(size_t)n * 256 + 1 * 64 + lane] = acc1 / l1 + bias[1 * 64 + lane];
  out[(size_t)n * 256 + 2 * 64 + lane] = acc2 / l2 + bias[2 * 64 + lane];
  out[(size_t)n * 256 + 3 * 64 + lane] = acc3 / l3 + bias[3 * 64 + lane];
}

// ---------------- GATv2 aggregation, layer 2 (1 head x 64) ----------------
__global__ void agg2_kernel(const float* __restrict__ xl, const float* __restrict__ xr,
                            const float* __restrict__ att, const float* __restrict__ bias,
                            const int* __restrict__ rowptr, const int* __restrict__ csr_src,
                            float* __restrict__ out) {
  int wave = threadIdx.x >> 6;
  int lane = threadIdx.x & 63;
  int n = blockIdx.x * 4 + wave;
  if (n >= N_NODES) return;

  float xi = xr[(size_t)n * 64 + lane];
  float attr = att[lane];
  float acc = 0.f, l = 0.f;
  int e0 = rowptr[n], e1 = rowptr[n + 1];
  for (int e = e0; e < e1; e++) {
    int s = csr_src[e];
    float xj = xl[(size_t)s * 64 + lane];
    float u = xi + xj;
    float v = fmaxf(u, NEG_SLOPE * u) * attr;
    v += __shfl_xor(v, 32);
    v += __shfl_xor(v, 16);
    v += __shfl_xor(v, 8);
    v += __shfl_xor(v, 4);
    v += __shfl_xor(v, 2);
    v += __shfl_xor(v, 1);
    float p = expf(v);
    acc += p * xj;
    l += p;
  }
  out[(size_t)n * 64 + lane] = acc / (l + 1e-16f) + bias[lane];
}

// ---------------- BatchNorm reduce ----------------
__global__ void bn_reduce_kernel(const float* __restrict__ x, float* __restrict__ sums,
                                 int C, int rowsPerBlock) {
  int tid = threadIdx.x;
  int c = tid % C;
  int rstep = blockDim.x / C;
  int r0 = blockIdx.x * rowsPerBlock + tid / C;
  int r1 = min(blockIdx.x * rowsPerBlock + rowsPerBlock, N_NODES);
  float s = 0.f, q = 0.f;
  for (int r = r0; r < r1; r += rstep) {
    float v = x[(size_t)r * C + c];
    s += v;
    q += v * v;
  }
  atomicAdd(&sums[c], s);
  atomicAdd(&sums[C + c], q);
}

// ---------------- BN finalize + exact GELU ----------------
__global__ void bn_gelu_kernel(const float* __restrict__ x, const float* __restrict__ sums,
                               const float* __restrict__ g, const float* __restrict__ b,
                               float* __restrict__ y, int C) {
  size_t total = (size_t)N_NODES * C;
  for (size_t i = blockIdx.x * (size_t)blockDim.x + threadIdx.x; i < total;
       i += (size_t)gridDim.x * blockDim.x) {
    int c = (int)(i % C);
    float mu = sums[c] * (1.0f / N_NODES);
    float var = sums[C + c] * (1.0f / N_NODES) - mu * mu;
    float v = (x[i] - mu) * rsqrtf(var + BN_EPS) * g[c] + b[c];
    y[i] = 0.5f * v * (1.f + erff(v * 0.70710678118f));
  }
}

// ---------------- classifier head + log_softmax ----------------
__global__ void head_kernel(const float* __restrict__ h, const float* __restrict__ Wc,
                            const float* __restrict__ bc, float* __restrict__ out) {
  __shared__ float Ws[HID * OUTC];
  __shared__ float bs[OUTC];
  for (int i = threadIdx.x; i < HID * OUTC; i += 256) Ws[i] = Wc[i];
  for (int i = threadIdx.x; i < OUTC; i += 256) bs[i] = bc[i];
  __syncthreads();

  int wave = threadIdx.x >> 6;
  int lane = threadIdx.x & 63;
  int n = blockIdx.x * 4 + wave;
  if (n >= N_NODES) return;

  float hrow = h[(size_t)n * HID + lane];
  float dot = 0.f;
#pragma unroll
  for (int k = 0; k < HID; k++) {
    float hk = __shfl(hrow, k);
    if (lane < OUTC) dot += hk * Ws[k * OUTC + lane];
  }
  float z = (lane < OUTC) ? (dot + bs[lane]) : -INFINITY;
  float mv = z;
  for (int off = 32; off; off >>= 1) mv = fmaxf(mv, __shfl_xor(mv, off));
  float p = (lane < OUTC) ? expf(z - mv) : 0.f;
  float sum = p;
  for (int off = 32; off; off >>= 1) sum += __shfl_xor(sum, off);
  if (lane < OUTC) out[(size_t)n * OUTC + lane] = z - mv - logf(sum);
}

// ---------------- launch ----------------
extern "C" void kernel_launch(void* const* d_in, const int* in_sizes, int n_in,
                              void* d_out, int out_size, void* d_ws, size_t ws_size,
                              hipStream_t stream) {
  const float* x = (const float*)d_in[0];
  const int* eidx = (const int*)d_in[1];
  const float* W1l = (const float*)d_in[2];
  const float* W1r = (const float*)d_in[3];
  const float* att1 = (const float*)d_in[4];
  const float* b1 = (const float*)d_in[5];
  const float* bn1_g = (const float*)d_in[6];
  const float* bn1_b = (const float*)d_in[7];
  const float* W2l = (const float*)d_in[8];
  const float* W2r = (const float*)d_in[9];
  const float* att2 = (const float*)d_in[10];
  const float* b2 = (const float*)d_in[11];
  const float* bn2_g = (const float*)d_in[12];
  const float* bn2_b = (const float*)d_in[13];
  const float* Wc = (const float*)d_in[14];
  const float* bc = (const float*)d_in[15];
  float* out = (float*)d_out;

  const int* src = eidx;
  const int* dstv = eidx + N_EDGES;

  char* ws = (char*)d_ws;
  // live-range-planned workspace:
  float* xl1 = (float*)(ws + 0);                 // [n][64] float4, 20,480,000
  float* xr1 = (float*)(ws + 20480000);          // 20,480,000
  float* out1 = (float*)(ws + 40960000);         // 20,480,000 (C0tmp -> out1 -> h1)
  float* out2 = (float*)(ws + 61440000);         // 5,120,000
  unsigned short* xb = (unsigned short*)(ws + 66560000);  // 10,240,000 (dies before xl2/xr2)
  float* xl2 = (float*)(ws + 66560000);          // 5,120,000 (reuses xb)
  float* xr2 = (float*)(ws + 71680000);          // 5,120,000
  int* deg = (int*)(ws + 76800000);
  int* cursor = (int*)(ws + 76880000);
  float* bnsum1 = (float*)(ws + 76960000);
  float* bnsum2 = (float*)(ws + 76962048);
  int* rowptr = (int*)(ws + 76962560);
  int* csr_src = (int*)(ws + 77042576);          // -> 78,322,576
  float* C1tmp = (float*)(ws + 78322576);        // 20,480,000 -> 98,802,576
  unsigned short* w1lb = (unsigned short*)(ws + 98802576);  // 131,072
  unsigned short* w1rb = (unsigned short*)(ws + 98933648);  // 131,072
  unsigned short* w2lb = (unsigned short*)(ws + 99064720);  // 32,768
  unsigned short* w2rb = (unsigned short*)(ws + 99097488);  // 32,768
  unsigned short* out1b = (unsigned short*)(ws + 0);        // reuses xl1 after agg1

  hipMemsetAsync(ws + 76800000, 0, 162560, stream);

  // casts
  cast_f32_bf16_kernel<<<5000, 256, 0, stream>>>(x, xb, 1280000);
  cast_weights_kernel<<<256, 256, 0, stream>>>(W1l, W1r, W2l, W2r, w1lb, w1rb, w2lb, w2rb);

  // layer-1 transforms (bf16 MFMA), standard layout
  gemm_bf16_kernel<<<dim3(4, 157), 256, 0, stream>>>(xb, w1lb, out1, N_NODES, 256, 256);
  gemm_bf16_kernel<<<dim3(4, 157), 256, 0, stream>>>(xb, w1rb, C1tmp, N_NODES, 256, 256);

  // CSR build
  hist_kernel<<<(N_EDGES + 255) / 256, 256, 0, stream>>>(dstv, deg);
  scan_kernel<<<1, 1024, 0, stream>>>(deg, rowptr);
  scatter_kernel<<<(N_EDGES + 255) / 256, 256, 0, stream>>>(src, dstv, rowptr, cursor, csr_src);

  // transpose to [n][d][h] float4 for the gather-heavy aggregation
  transpose_heads_kernel<<<5000, 256, 0, stream>>>(out1, C1tmp, (float4*)xl1, (float4*)xr1);

  // layer-1 attention aggregation (+bias), overwrites out1
  agg1_kernel<<<N_NODES / 4, 256, 0, stream>>>((const float4*)xl1, (const float4*)xr1,
                                               att1, b1, rowptr, csr_src, out1);

  // BN1 + GELU (in place)
  bn_reduce_kernel<<<800, 256, 0, stream>>>(out1, bnsum1, 256, 25);
  bn_gelu_kernel<<<2048, 256, 0, stream>>>(out1, bnsum1, bn1_g, bn1_b, out1, 256);

  // layer-2 transforms (bf16 MFMA)
  cast_f32_bf16_kernel<<<5000, 256, 0, stream>>>(out1, out1b, 1280000);
  gemm_bf16_kernel<<<dim3(1, 157), 256, 0, stream>>>(out1b, w2lb, xl2, N_NODES, 256, 64);
  gemm_bf16_kernel<<<dim3(1, 157), 256, 0, stream>>>(out1b, w2rb, xr2, N_NODES, 256, 64);

  // layer-2 attention aggregation (+bias)
  agg2_kernel<<<N_NODES / 4, 256, 0, stream>>>(xl2, xr2, att2, b2, rowptr, csr_src, out2);

  // BN2 + GELU (in place)
  bn_reduce_kernel<<<800, 256, 0, stream>>>(out2, bnsum2, 64, 25);
  bn_gelu_kernel<<<2048, 256, 0, stream>>>(out2, bnsum2, bn2_g, bn2_b, out2, 64);

  // classifier + log_softmax
  head_kernel<<<N_NODES / 4, 256, 0, stream>>>(out2, Wc, bc, out);
}

// Round 5
// 345.305 us; speedup vs baseline: 1.4616x; 1.2156x over previous
//
#include <hip/hip_runtime.h>
#include <math.h>

#define N_NODES 20000
#define N_EDGES 320000
#define NODE_DIM 256
#define HID 64
#define HEADS 4
#define OUTC 50
#define NEG_SLOPE 0.2f
#define BN_EPS 1e-5f

typedef __attribute__((ext_vector_type(8))) short short8;
typedef __attribute__((ext_vector_type(8))) unsigned short ushort8;
typedef __attribute__((ext_vector_type(4))) unsigned short ushort4v;
typedef __attribute__((ext_vector_type(4))) float f32x4;

__device__ inline unsigned short f2bf(float f) {
  unsigned u = __float_as_uint(f);
  u += 0x7fffu + ((u >> 16) & 1u);
  return (unsigned short)(u >> 16);
}

__device__ inline float gelu_exact(float v) {
  return 0.5f * v * (1.f + erff(v * 0.70710678118f));
}

// ---------------- casts ----------------
__global__ void cast_f32_bf16_kernel(const float* __restrict__ in,
                                     unsigned short* __restrict__ out, int n4) {
  int i = blockIdx.x * blockDim.x + threadIdx.x;
  if (i >= n4) return;
  float4 v = ((const float4*)in)[i];
  ushort4v o = {f2bf(v.x), f2bf(v.y), f2bf(v.z), f2bf(v.w)};
  ((ushort4v*)out)[i] = o;
}

// concat-cast weights: w1b[256][512] = [W1l | W1r], w2b[256][128] = [W2l | W2r]
__global__ void cast_weights_kernel(const float* __restrict__ W1l, const float* __restrict__ W1r,
                                    const float* __restrict__ W2l, const float* __restrict__ W2r,
                                    unsigned short* __restrict__ w1b,
                                    unsigned short* __restrict__ w2b) {
  int i = blockIdx.x * blockDim.x + threadIdx.x;
  if (i < 131072) {
    int k = i >> 9, j = i & 511;
    w1b[i] = f2bf(j < 256 ? W1l[k * 256 + j] : W1r[k * 256 + j - 256]);
  }
  if (i < 32768) {
    int k = i >> 7, j = i & 127;
    w2b[i] = f2bf(j < 64 ? W2l[k * 64 + j] : W2r[k * 64 + j - 64]);
  }
}

// ---------------- bf16 MFMA GEMM: C[M,N] = A[M,K] @ B[K,N] ----------------
// BM=128, BN=64, BK=32. 256 threads = 4 waves. (verified rounds 3)
__global__ __launch_bounds__(256) void gemm_bf16_kernel(
    const unsigned short* __restrict__ A, const unsigned short* __restrict__ B,
    float* __restrict__ C, int M, int K, int N) {
  __shared__ unsigned short As[128][40];
  __shared__ unsigned short Bs[64][40];
  int tid = threadIdx.x;
  int lane = tid & 63, w = tid >> 6;
  int bm = blockIdx.y * 128, bn = blockIdx.x * 64;

  f32x4 acc[2][4] = {};

  for (int k0 = 0; k0 < K; k0 += 32) {
#pragma unroll
    for (int s = tid; s < 512; s += 256) {
      int row = s >> 2, half = s & 3;
      int gr = bm + row;
      ushort8 v = {0, 0, 0, 0, 0, 0, 0, 0};
      if (gr < M) v = *(const ushort8*)&A[(size_t)gr * K + k0 + half * 8];
      *(ushort8*)&As[row][half * 8] = v;
    }
    {
      int k = tid >> 3, c0 = (tid & 7) * 8;
      ushort8 v = *(const ushort8*)&B[(size_t)(k0 + k) * N + bn + c0];
#pragma unroll
      for (int j = 0; j < 8; j++) Bs[c0 + j][k] = v[j];
    }
    __syncthreads();

    short8 av[2], bv[4];
#pragma unroll
    for (int fr = 0; fr < 2; fr++)
      av[fr] = *(const short8*)&As[w * 32 + fr * 16 + (lane & 15)][(lane >> 4) * 8];
#pragma unroll
    for (int fc = 0; fc < 4; fc++)
      bv[fc] = *(const short8*)&Bs[fc * 16 + (lane & 15)][(lane >> 4) * 8];
#pragma unroll
    for (int fr = 0; fr < 2; fr++)
#pragma unroll
      for (int fc = 0; fc < 4; fc++)
        acc[fr][fc] = __builtin_amdgcn_mfma_f32_16x16x32_bf16(av[fr], bv[fc], acc[fr][fc], 0, 0, 0);
    __syncthreads();
  }

#pragma unroll
  for (int fr = 0; fr < 2; fr++)
#pragma unroll
    for (int fc = 0; fc < 4; fc++)
#pragma unroll
      for (int i = 0; i < 4; i++) {
        int r = bm + w * 32 + fr * 16 + (lane >> 4) * 4 + i;
        if (r < M) C[(size_t)r * N + bn + fc * 16 + (lane & 15)] = acc[fr][fc][i];
      }
}

// ---------------- head transpose: C1full[n][512] -> xl/xr [n][d][h] float4 ----------------
__global__ void transpose_heads_kernel(const float* __restrict__ Cfull,
                                       float4* __restrict__ X0, float4* __restrict__ X1) {
  int i = blockIdx.x * blockDim.x + threadIdx.x;
  if (i >= N_NODES * 64) return;
  int n = i >> 6, d = i & 63;
  const float* r0 = Cfull + (size_t)n * 512;
  const float* r1 = r0 + 256;
  X0[i] = make_float4(r0[d], r0[64 + d], r0[128 + d], r0[192 + d]);
  X1[i] = make_float4(r1[d], r1[64 + d], r1[128 + d], r1[192 + d]);
}

// ---------------- CSR build ----------------
__global__ void hist_kernel(const int* __restrict__ dst, int* __restrict__ deg) {
  int i = blockIdx.x * blockDim.x + threadIdx.x;
  if (i < N_EDGES) atomicAdd(&deg[dst[i]], 1);
}

__global__ void scan_kernel(const int* __restrict__ deg, int* __restrict__ rowptr) {
  __shared__ int part[1024];
  int tid = threadIdx.x;
  const int CH = (N_NODES + 1023) / 1024;  // 20
  int base = tid * CH;
  int s = 0;
  for (int i = 0; i < CH; i++) {
    int idx = base + i;
    if (idx < N_NODES) s += deg[idx];
  }
  part[tid] = s;
  __syncthreads();
  for (int off = 1; off < 1024; off <<= 1) {
    int v = (tid >= off) ? part[tid - off] : 0;
    __syncthreads();
    part[tid] += v;
    __syncthreads();
  }
  int run = (tid == 0) ? 0 : part[tid - 1];
  for (int i = 0; i < CH; i++) {
    int idx = base + i;
    if (idx < N_NODES) {
      rowptr[idx] = run;
      run += deg[idx];
    }
  }
  if (tid == 1023) rowptr[N_NODES] = run;
}

__global__ void scatter_kernel(const int* __restrict__ src, const int* __restrict__ dst,
                               const int* __restrict__ rowptr, int* __restrict__ cursor,
                               int* __restrict__ csr_src) {
  int i = blockIdx.x * blockDim.x + threadIdx.x;
  if (i < N_EDGES) {
    int d = dst[i];
    int pos = rowptr[d] + atomicAdd(&cursor[d], 1);
    csr_src[pos] = src[i];
  }
}

// ---------------- GATv2 aggregation, layer 1 (4 heads x 64) ----------------
__global__ void agg1_kernel(const float4* __restrict__ xl, const float4* __restrict__ xr,
                            const float* __restrict__ att, const float* __restrict__ bias,
                            const int* __restrict__ rowptr, const int* __restrict__ csr_src,
                            float* __restrict__ out) {
  int wave = threadIdx.x >> 6;
  int lane = threadIdx.x & 63;
  int n = blockIdx.x * 4 + wave;
  if (n >= N_NODES) return;

  float4 xi = xr[(size_t)n * 64 + lane];
  float attr0 = att[0 * 64 + lane];
  float attr1 = att[1 * 64 + lane];
  float attr2 = att[2 * 64 + lane];
  float attr3 = att[3 * 64 + lane];

  float acc0 = 0.f, acc1 = 0.f, acc2 = 0.f, acc3 = 0.f;
  float lsum = 0.f;

  const bool hi32 = (lane & 32) != 0;
  const bool hi16 = (lane & 16) != 0;

  int e0 = rowptr[n], e1 = rowptr[n + 1];
  for (int e = e0; e < e1; e++) {
    int s = csr_src[e];
    float4 xj = xl[(size_t)s * 64 + lane];

    float u0 = xi.x + xj.x, u1 = xi.y + xj.y, u2 = xi.z + xj.z, u3 = xi.w + xj.w;
    float t0 = fmaxf(u0, NEG_SLOPE * u0) * attr0;
    float t1 = fmaxf(u1, NEG_SLOPE * u1) * attr1;
    float t2 = fmaxf(u2, NEG_SLOPE * u2) * attr2;
    float t3 = fmaxf(u3, NEG_SLOPE * u3) * attr3;

    float w0 = hi32 ? t2 : t0, y0 = hi32 ? t0 : t2;
    float w1 = hi32 ? t3 : t1, y1 = hi32 ? t1 : t3;
    w0 += __shfl_xor(y0, 32);
    w1 += __shfl_xor(y1, 32);
    float a = hi16 ? w1 : w0, b = hi16 ? w0 : w1;
    a += __shfl_xor(b, 16);
    a += __shfl_xor(a, 8);
    a += __shfl_xor(a, 4);
    a += __shfl_xor(a, 2);
    a += __shfl_xor(a, 1);

    float ev = expf(a);
    lsum += ev;

    float p0 = __shfl(ev, 0);
    float p1 = __shfl(ev, 16);
    float p2 = __shfl(ev, 32);
    float p3 = __shfl(ev, 48);
    acc0 += p0 * xj.x;
    acc1 += p1 * xj.y;
    acc2 += p2 * xj.z;
    acc3 += p3 * xj.w;
  }

  float l0 = __shfl(lsum, 0) + 1e-16f;
  float l1 = __shfl(lsum, 16) + 1e-16f;
  float l2 = __shfl(lsum, 32) + 1e-16f;
  float l3 = __shfl(lsum, 48) + 1e-16f;
  out[(size_t)n * 256 + 0 * 64 + lane] = acc0 / l0 + bias[0 * 64 + lane];
  out[(size_t)n * 256 + 1 * 64 + lane] = acc1 / l1 + bias[1 * 64 + lane];
  out[(size_t)n * 256 + 2 * 64 + lane] = acc2 / l2 + bias[2 * 64 + lane];
  out[(size_t)n * 256 + 3 * 64 + lane] = acc3 / l3 + bias[3 * 64 + lane];
}

// ---------------- GATv2 aggregation, layer 2 (combined [n][128] = [xl | xr]) ----------------
__global__ void agg2_kernel(const float* __restrict__ xlr,
                            const float* __restrict__ att, const float* __restrict__ bias,
                            const int* __restrict__ rowptr, const int* __restrict__ csr_src,
                            float* __restrict__ out) {
  int wave = threadIdx.x >> 6;
  int lane = threadIdx.x & 63;
  int n = blockIdx.x * 4 + wave;
  if (n >= N_NODES) return;

  float xi = xlr[(size_t)n * 128 + 64 + lane];
  float attr = att[lane];
  float acc = 0.f, l = 0.f;
  int e0 = rowptr[n], e1 = rowptr[n + 1];
  for (int e = e0; e < e1; e++) {
    int s = csr_src[e];
    float xj = xlr[(size_t)s * 128 + lane];
    float u = xi + xj;
    float v = fmaxf(u, NEG_SLOPE * u) * attr;
    v += __shfl_xor(v, 32);
    v += __shfl_xor(v, 16);
    v += __shfl_xor(v, 8);
    v += __shfl_xor(v, 4);
    v += __shfl_xor(v, 2);
    v += __shfl_xor(v, 1);
    float p = expf(v);
    acc += p * xj;
    l += p;
  }
  out[(size_t)n * 64 + lane] = acc / (l + 1e-16f) + bias[lane];
}

// ---------------- BN stage 1, C=256: per-block partial sum/sumsq ----------------
__global__ void bn_stage1_256_kernel(const float* __restrict__ x, float* __restrict__ partial) {
  int c = threadIdx.x;  // 256 threads, one channel each
  int r0 = blockIdx.x * 84;
  int r1 = min(r0 + 84, N_NODES);
  float s = 0.f, q = 0.f;
  for (int r = r0; r < r1; r++) {
    float v = x[(size_t)r * 256 + c];
    s += v;
    q += v * v;
  }
  partial[(size_t)blockIdx.x * 512 + c] = s;
  partial[(size_t)blockIdx.x * 512 + 256 + c] = q;
}

// ---------------- BN stage 1, C=64 ----------------
__global__ void bn_stage1_64_kernel(const float* __restrict__ x, float* __restrict__ partial) {
  __shared__ float ls[256], lq[256];
  int tid = threadIdx.x;
  int c = tid & 63, g = tid >> 6;  // 4 row-groups
  int r0 = blockIdx.x * 84 + g;
  int r1 = min(blockIdx.x * 84 + 84, N_NODES);
  float s = 0.f, q = 0.f;
  for (int r = r0; r < r1; r += 4) {
    float v = x[(size_t)r * 64 + c];
    s += v;
    q += v * v;
  }
  ls[tid] = s;
  lq[tid] = q;
  __syncthreads();
  if (g == 0) {
    s += ls[64 + c] + ls[128 + c] + ls[192 + c];
    q += lq[64 + c] + lq[128 + c] + lq[192 + c];
    partial[(size_t)blockIdx.x * 128 + c] = s;
    partial[(size_t)blockIdx.x * 128 + 64 + c] = q;
  }
}

// ---------------- BN stage 2: finalize scale/shift ----------------
__global__ void bn_stage2_kernel(const float* __restrict__ partial, int C,
                                 const float* __restrict__ gamma, const float* __restrict__ beta,
                                 float* __restrict__ ss) {
  int c = threadIdx.x;
  if (c >= C) return;
  float s = 0.f, q = 0.f;
  for (int b = 0; b < 240; b++) {
    s += partial[(size_t)b * 2 * C + c];
    q += partial[(size_t)b * 2 * C + C + c];
  }
  float mu = s * (1.0f / N_NODES);
  float var = q * (1.0f / N_NODES) - mu * mu;
  float sc = gamma[c] * rsqrtf(var + BN_EPS);
  ss[c] = sc;
  ss[C + c] = beta[c] - mu * sc;
}

// ---------------- BN finalize + GELU, layer 1 -> bf16 ----------------
__global__ void bn_gelu1_kernel(const float* __restrict__ x, const float* __restrict__ ss,
                                unsigned short* __restrict__ y) {
  const int total4 = N_NODES * 256 / 4;
  for (int i = blockIdx.x * blockDim.x + threadIdx.x; i < total4;
       i += gridDim.x * blockDim.x) {
    int c0 = (i & 63) * 4;
    float4 v = ((const float4*)x)[i];
    float a0 = gelu_exact(v.x * ss[c0 + 0] + ss[256 + c0 + 0]);
    float a1 = gelu_exact(v.y * ss[c0 + 1] + ss[256 + c0 + 1]);
    float a2 = gelu_exact(v.z * ss[c0 + 2] + ss[256 + c0 + 2]);
    float a3 = gelu_exact(v.w * ss[c0 + 3] + ss[256 + c0 + 3]);
    ushort4v o = {f2bf(a0), f2bf(a1), f2bf(a2), f2bf(a3)};
    ((ushort4v*)y)[i] = o;
  }
}

// ---------------- BN finalize + GELU, layer 2 -> f32 (in place) ----------------
__global__ void bn_gelu2_kernel(const float* __restrict__ x, const float* __restrict__ ss,
                                float* __restrict__ y) {
  const int total4 = N_NODES * 64 / 4;
  for (int i = blockIdx.x * blockDim.x + threadIdx.x; i < total4;
       i += gridDim.x * blockDim.x) {
    int c0 = (i & 15) * 4;
    float4 v = ((const float4*)x)[i];
    float4 o;
    o.x = gelu_exact(v.x * ss[c0 + 0] + ss[64 + c0 + 0]);
    o.y = gelu_exact(v.y * ss[c0 + 1] + ss[64 + c0 + 1]);
    o.z = gelu_exact(v.z * ss[c0 + 2] + ss[64 + c0 + 2]);
    o.w = gelu_exact(v.w * ss[c0 + 3] + ss[64 + c0 + 3]);
    ((float4*)y)[i] = o;
  }
}

// ---------------- classifier head + log_softmax ----------------
__global__ void head_kernel(const float* __restrict__ h, const float* __restrict__ Wc,
                            const float* __restrict__ bc, float* __restrict__ out) {
  __shared__ float Ws[HID * OUTC];
  __shared__ float bs[OUTC];
  for (int i = threadIdx.x; i < HID * OUTC; i += 256) Ws[i] = Wc[i];
  for (int i = threadIdx.x; i < OUTC; i += 256) bs[i] = bc[i];
  __syncthreads();

  int wave = threadIdx.x >> 6;
  int lane = threadIdx.x & 63;
  int n = blockIdx.x * 4 + wave;
  if (n >= N_NODES) return;

  float hrow = h[(size_t)n * HID + lane];
  float dot = 0.f;
#pragma unroll
  for (int k = 0; k < HID; k++) {
    float hk = __shfl(hrow, k);
    if (lane < OUTC) dot += hk * Ws[k * OUTC + lane];
  }
  float z = (lane < OUTC) ? (dot + bs[lane]) : -INFINITY;
  float mv = z;
  for (int off = 32; off; off >>= 1) mv = fmaxf(mv, __shfl_xor(mv, off));
  float p = (lane < OUTC) ? expf(z - mv) : 0.f;
  float sum = p;
  for (int off = 32; off; off >>= 1) sum += __shfl_xor(sum, off);
  if (lane < OUTC) out[(size_t)n * OUTC + lane] = z - mv - logf(sum);
}

// ---------------- launch ----------------
extern "C" void kernel_launch(void* const* d_in, const int* in_sizes, int n_in,
                              void* d_out, int out_size, void* d_ws, size_t ws_size,
                              hipStream_t stream) {
  const float* x = (const float*)d_in[0];
  const int* eidx = (const int*)d_in[1];
  const float* W1l = (const float*)d_in[2];
  const float* W1r = (const float*)d_in[3];
  const float* att1 = (const float*)d_in[4];
  const float* b1 = (const float*)d_in[5];
  const float* bn1_g = (const float*)d_in[6];
  const float* bn1_b = (const float*)d_in[7];
  const float* W2l = (const float*)d_in[8];
  const float* W2r = (const float*)d_in[9];
  const float* att2 = (const float*)d_in[10];
  const float* b2 = (const float*)d_in[11];
  const float* bn2_g = (const float*)d_in[12];
  const float* bn2_b = (const float*)d_in[13];
  const float* Wc = (const float*)d_in[14];
  const float* bc = (const float*)d_in[15];
  float* out = (float*)d_out;

  const int* src = eidx;
  const int* dstv = eidx + N_EDGES;

  char* ws = (char*)d_ws;
  // Workspace map (all offsets 16B-aligned; >=256B padding between independent regions).
  // Reuses (time-disjoint, one-kernel gap each):
  //   out1  over C1full[0..20.48M]      (C1full last read: transpose)
  //   out1b over C1full[20.48..30.72M]  (same)
  //   C2full over C1full[30.72..40.96M] (same)
  //   out2  over xb                     (xb last read: GEMM1)
  float* C1full = (float*)(ws + 0);                          // [20000][512] f32, 40,960,000
  float* out1 = (float*)(ws + 0);                            // [20000][256] f32
  unsigned short* out1b = (unsigned short*)(ws + 20480000);  // [20000][256] bf16
  float* C2full = (float*)(ws + 30720000);                   // [20000][128] f32
  float* xl1 = (float*)(ws + 41943040);                      // 20,480,000
  float* xr1 = (float*)(ws + 62914560);                      // 20,480,000
  unsigned short* xb = (unsigned short*)(ws + 83886080);     // 10,240,000
  float* out2 = (float*)(ws + 83886080);                     // 5,120,000 (after xb dead)
  float* partial = (float*)(ws + 94371840);                  // 240*512 f32 = 491,520
  float* ss1 = (float*)(ws + 94863360);                      // 512 f32
  float* ss2 = (float*)(ws + 94865408);                      // 128 f32
  unsigned short* w1b = (unsigned short*)(ws + 94865920);    // 262,144
  unsigned short* w2b = (unsigned short*)(ws + 95128064);    // 65,536
  int* deg = (int*)(ws + 95193600);                          // 80,000
  int* cursor = (int*)(ws + 95273600);                       // 80,000 (contiguous after deg)
  int* rowptr = (int*)(ws + 95353600);                       // 80,016
  int* csr_src = (int*)(ws + 95433616);                      // 1,280,000 -> ends 96,713,616

  hipMemsetAsync(deg, 0, 160000, stream);  // zeroes deg + cursor

  // casts
  cast_f32_bf16_kernel<<<5000, 256, 0, stream>>>(x, xb, 1280000);
  cast_weights_kernel<<<512, 256, 0, stream>>>(W1l, W1r, W2l, W2r, w1b, w2b);

  // layer-1 transform: one GEMM, N=512 ([xl | xr])
  gemm_bf16_kernel<<<dim3(8, 157), 256, 0, stream>>>(xb, w1b, C1full, N_NODES, 256, 512);

  // CSR build
  hist_kernel<<<(N_EDGES + 255) / 256, 256, 0, stream>>>(dstv, deg);
  scan_kernel<<<1, 1024, 0, stream>>>(deg, rowptr);
  scatter_kernel<<<(N_EDGES + 255) / 256, 256, 0, stream>>>(src, dstv, rowptr, cursor, csr_src);

  // transpose to [n][d][h] float4
  transpose_heads_kernel<<<5000, 256, 0, stream>>>(C1full, (float4*)xl1, (float4*)xr1);

  // layer-1 attention aggregation (+bias) -> out1
  agg1_kernel<<<N_NODES / 4, 256, 0, stream>>>((const float4*)xl1, (const float4*)xr1,
                                               att1, b1, rowptr, csr_src, out1);

  // BN1 (two-stage, atomic-free) + GELU -> bf16
  bn_stage1_256_kernel<<<240, 256, 0, stream>>>(out1, partial);
  bn_stage2_kernel<<<1, 256, 0, stream>>>(partial, 256, bn1_g, bn1_b, ss1);
  bn_gelu1_kernel<<<2048, 256, 0, stream>>>(out1, ss1, out1b);

  // layer-2 transform: one GEMM, N=128 ([xl2 | xr2])
  gemm_bf16_kernel<<<dim3(2, 157), 256, 0, stream>>>(out1b, w2b, C2full, N_NODES, 256, 128);

  // layer-2 attention aggregation (+bias)
  agg2_kernel<<<N_NODES / 4, 256, 0, stream>>>(C2full, att2, b2, rowptr, csr_src, out2);

  // BN2 + GELU (in place)
  bn_stage1_64_kernel<<<240, 256, 0, stream>>>(out2, partial);
  bn_stage2_kernel<<<1, 64, 0, stream>>>(partial, 64, bn2_g, bn2_b, ss2);
  bn_gelu2_kernel<<<1280, 256, 0, stream>>>(out2, ss2, out2);

  // classifier + log_softmax
  head_kernel<<<N_NODES / 4, 256, 0, stream>>>(out2, Wc, bc, out);
}

// Round 6
// 335.199 us; speedup vs baseline: 1.5057x; 1.0301x over previous
//
#include <hip/hip_runtime.h>
#include <math.h>

#define N_NODES 20000
#define N_EDGES 320000
#define NODE_DIM 256
#define HID 64
#define HEADS 4
#define OUTC 50
#define NEG_SLOPE 0.2f
#define BN_EPS 1e-5f

typedef __attribute__((ext_vector_type(8))) short short8;
typedef __attribute__((ext_vector_type(8))) unsigned short ushort8;
typedef __attribute__((ext_vector_type(4))) unsigned short ushort4v;
typedef __attribute__((ext_vector_type(4))) float f32x4;

__device__ inline unsigned short f2bf(float f) {
  unsigned u = __float_as_uint(f);
  u += 0x7fffu + ((u >> 16) & 1u);
  return (unsigned short)(u >> 16);
}

__device__ inline float bf2f(unsigned short u) {
  return __uint_as_float((unsigned)u << 16);
}

__device__ inline float gelu_exact(float v) {
  return 0.5f * v * (1.f + erff(v * 0.70710678118f));
}

// ---------------- casts ----------------
__global__ void cast_f32_bf16_kernel(const float* __restrict__ in,
                                     unsigned short* __restrict__ out, int n4) {
  int i = blockIdx.x * blockDim.x + threadIdx.x;
  if (i >= n4) return;
  float4 v = ((const float4*)in)[i];
  ushort4v o = {f2bf(v.x), f2bf(v.y), f2bf(v.z), f2bf(v.w)};
  ((ushort4v*)out)[i] = o;
}

// concat-cast weights: w1b[256][512] = [W1l | W1r], w2b[256][128] = [W2l | W2r]
__global__ void cast_weights_kernel(const float* __restrict__ W1l, const float* __restrict__ W1r,
                                    const float* __restrict__ W2l, const float* __restrict__ W2r,
                                    unsigned short* __restrict__ w1b,
                                    unsigned short* __restrict__ w2b) {
  int i = blockIdx.x * blockDim.x + threadIdx.x;
  if (i < 131072) {
    int k = i >> 9, j = i & 511;
    w1b[i] = f2bf(j < 256 ? W1l[k * 256 + j] : W1r[k * 256 + j - 256]);
  }
  if (i < 32768) {
    int k = i >> 7, j = i & 127;
    w2b[i] = f2bf(j < 64 ? W2l[k * 64 + j] : W2r[k * 64 + j - 64]);
  }
}

// ---------------- bf16 MFMA GEMM: C[M,N] = A[M,K] @ B[K,N] ----------------
// BM=128, BN=64, BK=32. 256 threads = 4 waves. BF16OUT: emit bf16 (RNE) C.
template <bool BF16OUT>
__global__ __launch_bounds__(256) void gemm_bf16_kernel(
    const unsigned short* __restrict__ A, const unsigned short* __restrict__ B,
    void* __restrict__ Cv, int M, int K, int N) {
  __shared__ unsigned short As[128][40];
  __shared__ unsigned short Bs[64][40];
  int tid = threadIdx.x;
  int lane = tid & 63, w = tid >> 6;
  int bm = blockIdx.y * 128, bn = blockIdx.x * 64;

  f32x4 acc[2][4] = {};

  for (int k0 = 0; k0 < K; k0 += 32) {
#pragma unroll
    for (int s = tid; s < 512; s += 256) {
      int row = s >> 2, half = s & 3;
      int gr = bm + row;
      ushort8 v = {0, 0, 0, 0, 0, 0, 0, 0};
      if (gr < M) v = *(const ushort8*)&A[(size_t)gr * K + k0 + half * 8];
      *(ushort8*)&As[row][half * 8] = v;
    }
    {
      int k = tid >> 3, c0 = (tid & 7) * 8;
      ushort8 v = *(const ushort8*)&B[(size_t)(k0 + k) * N + bn + c0];
#pragma unroll
      for (int j = 0; j < 8; j++) Bs[c0 + j][k] = v[j];
    }
    __syncthreads();

    short8 av[2], bv[4];
#pragma unroll
    for (int fr = 0; fr < 2; fr++)
      av[fr] = *(const short8*)&As[w * 32 + fr * 16 + (lane & 15)][(lane >> 4) * 8];
#pragma unroll
    for (int fc = 0; fc < 4; fc++)
      bv[fc] = *(const short8*)&Bs[fc * 16 + (lane & 15)][(lane >> 4) * 8];
#pragma unroll
    for (int fr = 0; fr < 2; fr++)
#pragma unroll
      for (int fc = 0; fc < 4; fc++)
        acc[fr][fc] = __builtin_amdgcn_mfma_f32_16x16x32_bf16(av[fr], bv[fc], acc[fr][fc], 0, 0, 0);
    __syncthreads();
  }

#pragma unroll
  for (int fr = 0; fr < 2; fr++)
#pragma unroll
    for (int fc = 0; fc < 4; fc++)
#pragma unroll
      for (int i = 0; i < 4; i++) {
        int r = bm + w * 32 + fr * 16 + (lane >> 4) * 4 + i;
        if (r < M) {
          size_t idx = (size_t)r * N + bn + fc * 16 + (lane & 15);
          if (BF16OUT)
            ((unsigned short*)Cv)[idx] = f2bf(acc[fr][fc][i]);
          else
            ((float*)Cv)[idx] = acc[fr][fc][i];
        }
      }
}

// ---------------- head transpose: C1full[n][512] bf16 -> xl/xr [n][d][h] bf16x4 ----------------
__global__ void transpose_heads_kernel(const unsigned short* __restrict__ Cfull,
                                       ushort4v* __restrict__ X0, ushort4v* __restrict__ X1) {
  int i = blockIdx.x * blockDim.x + threadIdx.x;
  if (i >= N_NODES * 64) return;
  int n = i >> 6, d = i & 63;
  const unsigned short* r0 = Cfull + (size_t)n * 512;
  ushort4v a = {r0[d], r0[64 + d], r0[128 + d], r0[192 + d]};
  ushort4v b = {r0[256 + d], r0[320 + d], r0[384 + d], r0[448 + d]};
  X0[i] = a;
  X1[i] = b;
}

// ---------------- CSR build ----------------
__global__ void hist_kernel(const int* __restrict__ dst, int* __restrict__ deg) {
  int i = blockIdx.x * blockDim.x + threadIdx.x;
  if (i < N_EDGES) atomicAdd(&deg[dst[i]], 1);
}

__global__ void scan_kernel(const int* __restrict__ deg, int* __restrict__ rowptr) {
  __shared__ int part[1024];
  int tid = threadIdx.x;
  const int CH = (N_NODES + 1023) / 1024;  // 20
  int base = tid * CH;
  int s = 0;
  for (int i = 0; i < CH; i++) {
    int idx = base + i;
    if (idx < N_NODES) s += deg[idx];
  }
  part[tid] = s;
  __syncthreads();
  for (int off = 1; off < 1024; off <<= 1) {
    int v = (tid >= off) ? part[tid - off] : 0;
    __syncthreads();
    part[tid] += v;
    __syncthreads();
  }
  int run = (tid == 0) ? 0 : part[tid - 1];
  for (int i = 0; i < CH; i++) {
    int idx = base + i;
    if (idx < N_NODES) {
      rowptr[idx] = run;
      run += deg[idx];
    }
  }
  if (tid == 1023) rowptr[N_NODES] = run;
}

__global__ void scatter_kernel(const int* __restrict__ src, const int* __restrict__ dst,
                               const int* __restrict__ rowptr, int* __restrict__ cursor,
                               int* __restrict__ csr_src) {
  int i = blockIdx.x * blockDim.x + threadIdx.x;
  if (i < N_EDGES) {
    int d = dst[i];
    int pos = rowptr[d] + atomicAdd(&cursor[d], 1);
    csr_src[pos] = src[i];
  }
}

// ---------------- GATv2 aggregation, layer 1 (4 heads x 64), bf16 messages ----------------
__global__ void agg1_kernel(const ushort4v* __restrict__ xl, const ushort4v* __restrict__ xr,
                            const float* __restrict__ att, const float* __restrict__ bias,
                            const int* __restrict__ rowptr, const int* __restrict__ csr_src,
                            float* __restrict__ out) {
  int wave = threadIdx.x >> 6;
  int lane = threadIdx.x & 63;
  int n = blockIdx.x * 4 + wave;
  if (n >= N_NODES) return;

  ushort4v xi4 = xr[(size_t)n * 64 + lane];
  float xi0 = bf2f(xi4[0]), xi1 = bf2f(xi4[1]), xi2 = bf2f(xi4[2]), xi3 = bf2f(xi4[3]);
  float attr0 = att[0 * 64 + lane];
  float attr1 = att[1 * 64 + lane];
  float attr2 = att[2 * 64 + lane];
  float attr3 = att[3 * 64 + lane];

  float acc0 = 0.f, acc1 = 0.f, acc2 = 0.f, acc3 = 0.f;
  float lsum = 0.f;

  const bool hi32 = (lane & 32) != 0;
  const bool hi16 = (lane & 16) != 0;

  int e0 = rowptr[n], e1 = rowptr[n + 1];
  for (int e = e0; e < e1; e++) {
    int s = csr_src[e];
    ushort4v xj4 = xl[(size_t)s * 64 + lane];
    float xj0 = bf2f(xj4[0]), xj1 = bf2f(xj4[1]), xj2 = bf2f(xj4[2]), xj3 = bf2f(xj4[3]);

    float u0 = xi0 + xj0, u1 = xi1 + xj1, u2 = xi2 + xj2, u3 = xi3 + xj3;
    float t0 = fmaxf(u0, NEG_SLOPE * u0) * attr0;
    float t1 = fmaxf(u1, NEG_SLOPE * u1) * attr1;
    float t2 = fmaxf(u2, NEG_SLOPE * u2) * attr2;
    float t3 = fmaxf(u3, NEG_SLOPE * u3) * attr3;

    // fold 4 independent 64-lane sums into 4 x 16-lane groups (7 shuffles)
    float w0 = hi32 ? t2 : t0, y0 = hi32 ? t0 : t2;
    float w1 = hi32 ? t3 : t1, y1 = hi32 ? t1 : t3;
    w0 += __shfl_xor(y0, 32);
    w1 += __shfl_xor(y1, 32);
    float a = hi16 ? w1 : w0, b = hi16 ? w0 : w1;
    a += __shfl_xor(b, 16);
    a += __shfl_xor(a, 8);
    a += __shfl_xor(a, 4);
    a += __shfl_xor(a, 2);
    a += __shfl_xor(a, 1);

    float ev = expf(a);
    lsum += ev;

    float p0 = __shfl(ev, 0);
    float p1 = __shfl(ev, 16);
    float p2 = __shfl(ev, 32);
    float p3 = __shfl(ev, 48);
    acc0 += p0 * xj0;
    acc1 += p1 * xj1;
    acc2 += p2 * xj2;
    acc3 += p3 * xj3;
  }

  float l0 = __shfl(lsum, 0) + 1e-16f;
  float l1 = __shfl(lsum, 16) + 1e-16f;
  float l2 = __shfl(lsum, 32) + 1e-16f;
  float l3 = __shfl(lsum, 48) + 1e-16f;
  out[(size_t)n * 256 + 0 * 64 + lane] = acc0 / l0 + bias[0 * 64 + lane];
  out[(size_t)n * 256 + 1 * 64 + lane] = acc1 / l1 + bias[1 * 64 + lane];
  out[(size_t)n * 256 + 2 * 64 + lane] = acc2 / l2 + bias[2 * 64 + lane];
  out[(size_t)n * 256 + 3 * 64 + lane] = acc3 / l3 + bias[3 * 64 + lane];
}

// ---------------- GATv2 aggregation, layer 2 (combined [n][128] bf16 = [xl | xr]) ----------------
__global__ void agg2_kernel(const unsigned short* __restrict__ xlr,
                            const float* __restrict__ att, const float* __restrict__ bias,
                            const int* __restrict__ rowptr, const int* __restrict__ csr_src,
                            float* __restrict__ out) {
  int wave = threadIdx.x >> 6;
  int lane = threadIdx.x & 63;
  int n = blockIdx.x * 4 + wave;
  if (n >= N_NODES) return;

  float xi = bf2f(xlr[(size_t)n * 128 + 64 + lane]);
  float attr = att[lane];
  float acc = 0.f, l = 0.f;
  int e0 = rowptr[n], e1 = rowptr[n + 1];
  for (int e = e0; e < e1; e++) {
    int s = csr_src[e];
    float xj = bf2f(xlr[(size_t)s * 128 + lane]);
    float u = xi + xj;
    float v = fmaxf(u, NEG_SLOPE * u) * attr;
    v += __shfl_xor(v, 32);
    v += __shfl_xor(v, 16);
    v += __shfl_xor(v, 8);
    v += __shfl_xor(v, 4);
    v += __shfl_xor(v, 2);
    v += __shfl_xor(v, 1);
    float p = expf(v);
    acc += p * xj;
    l += p;
  }
  out[(size_t)n * 64 + lane] = acc / (l + 1e-16f) + bias[lane];
}

// ---------------- BN stage 1, C=256 ----------------
__global__ void bn_stage1_256_kernel(const float* __restrict__ x, float* __restrict__ partial) {
  int c = threadIdx.x;
  int r0 = blockIdx.x * 84;
  int r1 = min(r0 + 84, N_NODES);
  float s = 0.f, q = 0.f;
  for (int r = r0; r < r1; r++) {
    float v = x[(size_t)r * 256 + c];
    s += v;
    q += v * v;
  }
  partial[(size_t)blockIdx.x * 512 + c] = s;
  partial[(size_t)blockIdx.x * 512 + 256 + c] = q;
}

// ---------------- BN stage 1, C=64 ----------------
__global__ void bn_stage1_64_kernel(const float* __restrict__ x, float* __restrict__ partial) {
  __shared__ float ls[256], lq[256];
  int tid = threadIdx.x;
  int c = tid & 63, g = tid >> 6;
  int r0 = blockIdx.x * 84 + g;
  int r1 = min(blockIdx.x * 84 + 84, N_NODES);
  float s = 0.f, q = 0.f;
  for (int r = r0; r < r1; r += 4) {
    float v = x[(size_t)r * 64 + c];
    s += v;
    q += v * v;
  }
  ls[tid] = s;
  lq[tid] = q;
  __syncthreads();
  if (g == 0) {
    s += ls[64 + c] + ls[128 + c] + ls[192 + c];
    q += lq[64 + c] + lq[128 + c] + lq[192 + c];
    partial[(size_t)blockIdx.x * 128 + c] = s;
    partial[(size_t)blockIdx.x * 128 + 64 + c] = q;
  }
}

// ---------------- BN stage 2: finalize scale/shift ----------------
__global__ void bn_stage2_kernel(const float* __restrict__ partial, int C,
                                 const float* __restrict__ gamma, const float* __restrict__ beta,
                                 float* __restrict__ ss) {
  int c = threadIdx.x;
  if (c >= C) return;
  float s = 0.f, q = 0.f;
  for (int b = 0; b < 240; b++) {
    s += partial[(size_t)b * 2 * C + c];
    q += partial[(size_t)b * 2 * C + C + c];
  }
  float mu = s * (1.0f / N_NODES);
  float var = q * (1.0f / N_NODES) - mu * mu;
  float sc = gamma[c] * rsqrtf(var + BN_EPS);
  ss[c] = sc;
  ss[C + c] = beta[c] - mu * sc;
}

// ---------------- BN finalize + GELU, layer 1 -> bf16 ----------------
__global__ void bn_gelu1_kernel(const float* __restrict__ x, const float* __restrict__ ss,
                                unsigned short* __restrict__ y) {
  const int total4 = N_NODES * 256 / 4;
  for (int i = blockIdx.x * blockDim.x + threadIdx.x; i < total4;
       i += gridDim.x * blockDim.x) {
    int c0 = (i & 63) * 4;
    float4 v = ((const float4*)x)[i];
    float a0 = gelu_exact(v.x * ss[c0 + 0] + ss[256 + c0 + 0]);
    float a1 = gelu_exact(v.y * ss[c0 + 1] + ss[256 + c0 + 1]);
    float a2 = gelu_exact(v.z * ss[c0 + 2] + ss[256 + c0 + 2]);
    float a3 = gelu_exact(v.w * ss[c0 + 3] + ss[256 + c0 + 3]);
    ushort4v o = {f2bf(a0), f2bf(a1), f2bf(a2), f2bf(a3)};
    ((ushort4v*)y)[i] = o;
  }
}

// ---------------- BN finalize + GELU, layer 2 -> f32 (in place) ----------------
__global__ void bn_gelu2_kernel(const float* __restrict__ x, const float* __restrict__ ss,
                                float* __restrict__ y) {
  const int total4 = N_NODES * 64 / 4;
  for (int i = blockIdx.x * blockDim.x + threadIdx.x; i < total4;
       i += gridDim.x * blockDim.x) {
    int c0 = (i & 15) * 4;
    float4 v = ((const float4*)x)[i];
    float4 o;
    o.x = gelu_exact(v.x * ss[c0 + 0] + ss[64 + c0 + 0]);
    o.y = gelu_exact(v.y * ss[c0 + 1] + ss[64 + c0 + 1]);
    o.z = gelu_exact(v.z * ss[c0 + 2] + ss[64 + c0 + 2]);
    o.w = gelu_exact(v.w * ss[c0 + 3] + ss[64 + c0 + 3]);
    ((float4*)y)[i] = o;
  }
}

// ---------------- classifier head + log_softmax ----------------
__global__ void head_kernel(const float* __restrict__ h, const float* __restrict__ Wc,
                            const float* __restrict__ bc, float* __restrict__ out) {
  __shared__ float Ws[HID * OUTC];
  __shared__ float bs[OUTC];
  for (int i = threadIdx.x; i < HID * OUTC; i += 256) Ws[i] = Wc[i];
  for (int i = threadIdx.x; i < OUTC; i += 256) bs[i] = bc[i];
  __syncthreads();

  int wave = threadIdx.x >> 6;
  int lane = threadIdx.x & 63;
  int n = blockIdx.x * 4 + wave;
  if (n >= N_NODES) return;

  float hrow = h[(size_t)n * HID + lane];
  float dot = 0.f;
#pragma unroll
  for (int k = 0; k < HID; k++) {
    float hk = __shfl(hrow, k);
    if (lane < OUTC) dot += hk * Ws[k * OUTC + lane];
  }
  float z = (lane < OUTC) ? (dot + bs[lane]) : -INFINITY;
  float mv = z;
  for (int off = 32; off; off >>= 1) mv = fmaxf(mv, __shfl_xor(mv, off));
  float p = (lane < OUTC) ? expf(z - mv) : 0.f;
  float sum = p;
  for (int off = 32; off; off >>= 1) sum += __shfl_xor(sum, off);
  if (lane < OUTC) out[(size_t)n * OUTC + lane] = z - mv - logf(sum);
}

// ---------------- launch ----------------
extern "C" void kernel_launch(void* const* d_in, const int* in_sizes, int n_in,
                              void* d_out, int out_size, void* d_ws, size_t ws_size,
                              hipStream_t stream) {
  const float* x = (const float*)d_in[0];
  const int* eidx = (const int*)d_in[1];
  const float* W1l = (const float*)d_in[2];
  const float* W1r = (const float*)d_in[3];
  const float* att1 = (const float*)d_in[4];
  const float* b1 = (const float*)d_in[5];
  const float* bn1_g = (const float*)d_in[6];
  const float* bn1_b = (const float*)d_in[7];
  const float* W2l = (const float*)d_in[8];
  const float* W2r = (const float*)d_in[9];
  const float* att2 = (const float*)d_in[10];
  const float* b2 = (const float*)d_in[11];
  const float* bn2_g = (const float*)d_in[12];
  const float* bn2_b = (const float*)d_in[13];
  const float* Wc = (const float*)d_in[14];
  const float* bc = (const float*)d_in[15];
  float* out = (float*)d_out;

  const int* src = eidx;
  const int* dstv = eidx + N_EDGES;

  char* ws = (char*)d_ws;
  // Workspace map. Time-disjoint reuses (one-kernel separation each):
  //   out1 (f32, 20.48MB) over C1full (bf16, 20.48MB): C1full last read = transpose
  //   out2 (f32, 5.12MB)  over xb (bf16, 10.24MB):     xb last read = GEMM1
  unsigned short* C1full = (unsigned short*)(ws + 0);        // [20000][512] bf16, 20,480,000
  float* out1 = (float*)(ws + 0);                            // [20000][256] f32
  unsigned short* out1b = (unsigned short*)(ws + 20971520);  // [20000][256] bf16, 10,240,000
  unsigned short* C2full = (unsigned short*)(ws + 31457280); // [20000][128] bf16, 5,120,000
  unsigned short* xl1 = (unsigned short*)(ws + 41943040);    // [n][64] bf16x4, 10,240,000
  unsigned short* xr1 = (unsigned short*)(ws + 52428800);    // 10,240,000
  unsigned short* xb = (unsigned short*)(ws + 62914560);     // [20000][256] bf16, 10,240,000
  float* out2 = (float*)(ws + 62914560);                     // 5,120,000 (after xb dead)
  float* partial = (float*)(ws + 73400320);                  // 240*512 f32 = 491,520
  float* ss1 = (float*)(ws + 73891840);                      // 512 f32
  float* ss2 = (float*)(ws + 73893888);                      // 128 f32
  unsigned short* w1b = (unsigned short*)(ws + 73894400);    // 262,144
  unsigned short* w2b = (unsigned short*)(ws + 74156544);    // 65,536
  int* deg = (int*)(ws + 74222080);                          // 80,000
  int* cursor = (int*)(ws + 74302080);                       // 80,000 (contiguous)
  int* rowptr = (int*)(ws + 74382080);                       // 80,016
  int* csr_src = (int*)(ws + 74462096);                      // 1,280,000 -> ends 75,742,096

  hipMemsetAsync(deg, 0, 160000, stream);  // deg + cursor

  // casts
  cast_f32_bf16_kernel<<<5000, 256, 0, stream>>>(x, xb, 1280000);
  cast_weights_kernel<<<512, 256, 0, stream>>>(W1l, W1r, W2l, W2r, w1b, w2b);

  // layer-1 transform: one GEMM, N=512 ([xl | xr]), bf16 out
  gemm_bf16_kernel<true><<<dim3(8, 157), 256, 0, stream>>>(xb, w1b, C1full, N_NODES, 256, 512);

  // CSR build
  hist_kernel<<<(N_EDGES + 255) / 256, 256, 0, stream>>>(dstv, deg);
  scan_kernel<<<1, 1024, 0, stream>>>(deg, rowptr);
  scatter_kernel<<<(N_EDGES + 255) / 256, 256, 0, stream>>>(src, dstv, rowptr, cursor, csr_src);

  // transpose to [n][d][h] bf16x4
  transpose_heads_kernel<<<5000, 256, 0, stream>>>(C1full, (ushort4v*)xl1, (ushort4v*)xr1);

  // layer-1 attention aggregation (+bias) -> out1 (f32)
  agg1_kernel<<<N_NODES / 4, 256, 0, stream>>>((const ushort4v*)xl1, (const ushort4v*)xr1,
                                               att1, b1, rowptr, csr_src, out1);

  // BN1 (two-stage, atomic-free) + GELU -> bf16
  bn_stage1_256_kernel<<<240, 256, 0, stream>>>(out1, partial);
  bn_stage2_kernel<<<1, 256, 0, stream>>>(partial, 256, bn1_g, bn1_b, ss1);
  bn_gelu1_kernel<<<2048, 256, 0, stream>>>(out1, ss1, out1b);

  // layer-2 transform: one GEMM, N=128 ([xl2 | xr2]), bf16 out
  gemm_bf16_kernel<true><<<dim3(2, 157), 256, 0, stream>>>(out1b, w2b, C2full, N_NODES, 256, 128);

  // layer-2 attention aggregation (+bias)
  agg2_kernel<<<N_NODES / 4, 256, 0, stream>>>(C2full, att2, b2, rowptr, csr_src, out2);

  // BN2 + GELU (in place)
  bn_stage1_64_kernel<<<240, 256, 0, stream>>>(out2, partial);
  bn_stage2_kernel<<<1, 64, 0, stream>>>(partial, 64, bn2_g, bn2_b, ss2);
  bn_gelu2_kernel<<<1280, 256, 0, stream>>>(out2, ss2, out2);

  // classifier + log_softmax
  head_kernel<<<N_NODES / 4, 256, 0, stream>>>(out2, Wc, bc, out);
}

// Round 7
// 278.301 us; speedup vs baseline: 1.8136x; 1.2044x over previous
//
#include <hip/hip_runtime.h>
#include <math.h>

#define N_NODES 20000
#define N_EDGES 320000
#define NODE_DIM 256
#define HID 64
#define HEADS 4
#define OUTC 50
#define NEG_SLOPE 0.2f
#define BN_EPS 1e-5f

typedef __attribute__((ext_vector_type(8))) short short8;
typedef __attribute__((ext_vector_type(8))) unsigned short ushort8;
typedef __attribute__((ext_vector_type(4))) unsigned short ushort4v;
typedef __attribute__((ext_vector_type(4))) float f32x4;

__device__ inline unsigned short f2bf(float f) {
  unsigned u = __float_as_uint(f);
  u += 0x7fffu + ((u >> 16) & 1u);
  return (unsigned short)(u >> 16);
}

__device__ inline float bf2f(unsigned short u) {
  return __uint_as_float((unsigned)u << 16);
}

__device__ inline float gelu_exact(float v) {
  return 0.5f * v * (1.f + erff(v * 0.70710678118f));
}

// ---------------- casts ----------------
__global__ void cast_f32_bf16_kernel(const float* __restrict__ in,
                                     unsigned short* __restrict__ out, int n4) {
  int i = blockIdx.x * blockDim.x + threadIdx.x;
  if (i >= n4) return;
  float4 v = ((const float4*)in)[i];
  ushort4v o = {f2bf(v.x), f2bf(v.y), f2bf(v.z), f2bf(v.w)};
  ((ushort4v*)out)[i] = o;
}

// concat-cast weights: w1b[256][512] = [W1l | W1r], w2b[256][128] = [W2l | W2r]
__global__ void cast_weights_kernel(const float* __restrict__ W1l, const float* __restrict__ W1r,
                                    const float* __restrict__ W2l, const float* __restrict__ W2r,
                                    unsigned short* __restrict__ w1b,
                                    unsigned short* __restrict__ w2b) {
  int i = blockIdx.x * blockDim.x + threadIdx.x;
  if (i < 131072) {
    int k = i >> 9, j = i & 511;
    w1b[i] = f2bf(j < 256 ? W1l[k * 256 + j] : W1r[k * 256 + j - 256]);
  }
  if (i < 32768) {
    int k = i >> 7, j = i & 127;
    w2b[i] = f2bf(j < 64 ? W2l[k * 64 + j] : W2r[k * 64 + j - 64]);
  }
}

// ---------------- bf16 MFMA GEMM: C[M,N] = A[M,K] @ B[K,N], bf16 out ----------------
// BM=128, BN=64, BK=32. 256 threads = 4 waves.
__global__ __launch_bounds__(256) void gemm_bf16_kernel(
    const unsigned short* __restrict__ A, const unsigned short* __restrict__ B,
    unsigned short* __restrict__ C, int M, int K, int N) {
  __shared__ unsigned short As[128][40];
  __shared__ unsigned short Bs[64][40];
  int tid = threadIdx.x;
  int lane = tid & 63, w = tid >> 6;
  int bm = blockIdx.y * 128, bn = blockIdx.x * 64;

  f32x4 acc[2][4] = {};

  for (int k0 = 0; k0 < K; k0 += 32) {
#pragma unroll
    for (int s = tid; s < 512; s += 256) {
      int row = s >> 2, half = s & 3;
      int gr = bm + row;
      ushort8 v = {0, 0, 0, 0, 0, 0, 0, 0};
      if (gr < M) v = *(const ushort8*)&A[(size_t)gr * K + k0 + half * 8];
      *(ushort8*)&As[row][half * 8] = v;
    }
    {
      int k = tid >> 3, c0 = (tid & 7) * 8;
      ushort8 v = *(const ushort8*)&B[(size_t)(k0 + k) * N + bn + c0];
#pragma unroll
      for (int j = 0; j < 8; j++) Bs[c0 + j][k] = v[j];
    }
    __syncthreads();

    short8 av[2], bv[4];
#pragma unroll
    for (int fr = 0; fr < 2; fr++)
      av[fr] = *(const short8*)&As[w * 32 + fr * 16 + (lane & 15)][(lane >> 4) * 8];
#pragma unroll
    for (int fc = 0; fc < 4; fc++)
      bv[fc] = *(const short8*)&Bs[fc * 16 + (lane & 15)][(lane >> 4) * 8];
#pragma unroll
    for (int fr = 0; fr < 2; fr++)
#pragma unroll
      for (int fc = 0; fc < 4; fc++)
        acc[fr][fc] = __builtin_amdgcn_mfma_f32_16x16x32_bf16(av[fr], bv[fc], acc[fr][fc], 0, 0, 0);
    __syncthreads();
  }

#pragma unroll
  for (int fr = 0; fr < 2; fr++)
#pragma unroll
    for (int fc = 0; fc < 4; fc++)
#pragma unroll
      for (int i = 0; i < 4; i++) {
        int r = bm + w * 32 + fr * 16 + (lane >> 4) * 4 + i;
        if (r < M) C[(size_t)r * N + bn + fc * 16 + (lane & 15)] = f2bf(acc[fr][fc][i]);
      }
}

// ---------------- CSR build ----------------
__global__ void hist_kernel(const int* __restrict__ dst, int* __restrict__ deg) {
  int i = blockIdx.x * blockDim.x + threadIdx.x;
  if (i < N_EDGES) atomicAdd(&deg[dst[i]], 1);
}

__global__ void scan_kernel(const int* __restrict__ deg, int* __restrict__ rowptr) {
  __shared__ int part[1024];
  int tid = threadIdx.x;
  const int CH = (N_NODES + 1023) / 1024;  // 20
  int base = tid * CH;
  int s = 0;
  for (int i = 0; i < CH; i++) {
    int idx = base + i;
    if (idx < N_NODES) s += deg[idx];
  }
  part[tid] = s;
  __syncthreads();
  for (int off = 1; off < 1024; off <<= 1) {
    int v = (tid >= off) ? part[tid - off] : 0;
    __syncthreads();
    part[tid] += v;
    __syncthreads();
  }
  int run = (tid == 0) ? 0 : part[tid - 1];
  for (int i = 0; i < CH; i++) {
    int idx = base + i;
    if (idx < N_NODES) {
      rowptr[idx] = run;
      run += deg[idx];
    }
  }
  if (tid == 1023) rowptr[N_NODES] = run;
}

__global__ void scatter_kernel(const int* __restrict__ src, const int* __restrict__ dst,
                               const int* __restrict__ rowptr, int* __restrict__ cursor,
                               int* __restrict__ csr_src) {
  int i = blockIdx.x * blockDim.x + threadIdx.x;
  if (i < N_EDGES) {
    int d = dst[i];
    int pos = rowptr[d] + atomicAdd(&cursor[d], 1);
    csr_src[pos] = src[i];
  }
}

// ---------------- GATv2 aggregation, layer 1 ----------------
// Wave per node. Lane l: head h=l>>4, channels c=4l..4l+3 (of head h's 64 dims).
// Score reduce = 4-step butterfly within the 16-lane group; no broadcasts.
// C1 = [n][512] bf16 rows: [xl(256) | xr(256)] in standard [h][d] layout.
__global__ void agg1_kernel(const unsigned short* __restrict__ C1,
                            const float* __restrict__ att, const float* __restrict__ bias,
                            const int* __restrict__ rowptr, const int* __restrict__ csr_src,
                            float* __restrict__ out) {
  int wave = threadIdx.x >> 6;
  int lane = threadIdx.x & 63;
  int n = blockIdx.x * 4 + wave;
  if (n >= N_NODES) return;

  ushort4v xi4 = *(const ushort4v*)&C1[(size_t)n * 512 + 256 + 4 * lane];
  float xi0 = bf2f(xi4[0]), xi1 = bf2f(xi4[1]), xi2 = bf2f(xi4[2]), xi3 = bf2f(xi4[3]);
  float4 attv = *(const float4*)&att[4 * lane];

  float acc0 = 0.f, acc1 = 0.f, acc2 = 0.f, acc3 = 0.f;
  float lsum = 0.f;

  int e0 = rowptr[n], e1 = rowptr[n + 1];
  int e = e0;
  for (; e + 2 <= e1; e += 2) {
    int s0 = csr_src[e];
    int s1 = csr_src[e + 1];
    ushort4v a4 = *(const ushort4v*)&C1[(size_t)s0 * 512 + 4 * lane];
    ushort4v b4 = *(const ushort4v*)&C1[(size_t)s1 * 512 + 4 * lane];
    float xa0 = bf2f(a4[0]), xa1 = bf2f(a4[1]), xa2 = bf2f(a4[2]), xa3 = bf2f(a4[3]);
    float xb0 = bf2f(b4[0]), xb1 = bf2f(b4[1]), xb2 = bf2f(b4[2]), xb3 = bf2f(b4[3]);

    float ua0 = xi0 + xa0, ua1 = xi1 + xa1, ua2 = xi2 + xa2, ua3 = xi3 + xa3;
    float ub0 = xi0 + xb0, ub1 = xi1 + xb1, ub2 = xi2 + xb2, ub3 = xi3 + xb3;
    float ta = fmaxf(ua0, NEG_SLOPE * ua0) * attv.x + fmaxf(ua1, NEG_SLOPE * ua1) * attv.y +
               fmaxf(ua2, NEG_SLOPE * ua2) * attv.z + fmaxf(ua3, NEG_SLOPE * ua3) * attv.w;
    float tb = fmaxf(ub0, NEG_SLOPE * ub0) * attv.x + fmaxf(ub1, NEG_SLOPE * ub1) * attv.y +
               fmaxf(ub2, NEG_SLOPE * ub2) * attv.z + fmaxf(ub3, NEG_SLOPE * ub3) * attv.w;

    ta += __shfl_xor(ta, 8);  tb += __shfl_xor(tb, 8);
    ta += __shfl_xor(ta, 4);  tb += __shfl_xor(tb, 4);
    ta += __shfl_xor(ta, 2);  tb += __shfl_xor(tb, 2);
    ta += __shfl_xor(ta, 1);  tb += __shfl_xor(tb, 1);

    float pa = expf(ta);
    float pb = expf(tb);
    lsum += pa + pb;
    acc0 += pa * xa0 + pb * xb0;
    acc1 += pa * xa1 + pb * xb1;
    acc2 += pa * xa2 + pb * xb2;
    acc3 += pa * xa3 + pb * xb3;
  }
  if (e < e1) {
    int s0 = csr_src[e];
    ushort4v a4 = *(const ushort4v*)&C1[(size_t)s0 * 512 + 4 * lane];
    float xa0 = bf2f(a4[0]), xa1 = bf2f(a4[1]), xa2 = bf2f(a4[2]), xa3 = bf2f(a4[3]);
    float ua0 = xi0 + xa0, ua1 = xi1 + xa1, ua2 = xi2 + xa2, ua3 = xi3 + xa3;
    float ta = fmaxf(ua0, NEG_SLOPE * ua0) * attv.x + fmaxf(ua1, NEG_SLOPE * ua1) * attv.y +
               fmaxf(ua2, NEG_SLOPE * ua2) * attv.z + fmaxf(ua3, NEG_SLOPE * ua3) * attv.w;
    ta += __shfl_xor(ta, 8);
    ta += __shfl_xor(ta, 4);
    ta += __shfl_xor(ta, 2);
    ta += __shfl_xor(ta, 1);
    float pa = expf(ta);
    lsum += pa;
    acc0 += pa * xa0;
    acc1 += pa * xa1;
    acc2 += pa * xa2;
    acc3 += pa * xa3;
  }

  float inv = 1.f / (lsum + 1e-16f);
  float4 bv = *(const float4*)&bias[4 * lane];
  float4 o;
  o.x = acc0 * inv + bv.x;
  o.y = acc1 * inv + bv.y;
  o.z = acc2 * inv + bv.z;
  o.w = acc3 * inv + bv.w;
  *(float4*)&out[(size_t)n * 256 + 4 * lane] = o;
}

// ---------------- GATv2 aggregation, layer 2 ----------------
// Wave per node; 4 x 16-lane groups each process a different edge (4 dims/lane).
// xlr = [n][128] bf16: [xl(64) | xr(64)].
__global__ void agg2_kernel(const unsigned short* __restrict__ xlr,
                            const float* __restrict__ att, const float* __restrict__ bias,
                            const int* __restrict__ rowptr, const int* __restrict__ csr_src,
                            float* __restrict__ out) {
  int wave = threadIdx.x >> 6;
  int lane = threadIdx.x & 63;
  int n = blockIdx.x * 4 + wave;
  if (n >= N_NODES) return;

  int g = lane >> 4, slot = lane & 15;
  ushort4v xi4 = *(const ushort4v*)&xlr[(size_t)n * 128 + 64 + 4 * slot];
  float xi0 = bf2f(xi4[0]), xi1 = bf2f(xi4[1]), xi2 = bf2f(xi4[2]), xi3 = bf2f(xi4[3]);
  float4 attv = *(const float4*)&att[4 * slot];

  float acc0 = 0.f, acc1 = 0.f, acc2 = 0.f, acc3 = 0.f;
  float lsum = 0.f;

  int e0 = rowptr[n], e1 = rowptr[n + 1];
  int nt = (e1 - e0 + 3) >> 2;
  for (int it = 0; it < nt; it++) {
    int e = e0 + it * 4 + g;
    bool valid = e < e1;
    int s = valid ? csr_src[e] : 0;
    ushort4v xj4 = *(const ushort4v*)&xlr[(size_t)s * 128 + 4 * slot];
    float xj0 = bf2f(xj4[0]), xj1 = bf2f(xj4[1]), xj2 = bf2f(xj4[2]), xj3 = bf2f(xj4[3]);
    float u0 = xi0 + xj0, u1 = xi1 + xj1, u2 = xi2 + xj2, u3 = xi3 + xj3;
    float t = fmaxf(u0, NEG_SLOPE * u0) * attv.x + fmaxf(u1, NEG_SLOPE * u1) * attv.y +
              fmaxf(u2, NEG_SLOPE * u2) * attv.z + fmaxf(u3, NEG_SLOPE * u3) * attv.w;
    t += __shfl_xor(t, 8);
    t += __shfl_xor(t, 4);
    t += __shfl_xor(t, 2);
    t += __shfl_xor(t, 1);
    float p = valid ? expf(t) : 0.f;
    lsum += p;
    acc0 += p * xj0;
    acc1 += p * xj1;
    acc2 += p * xj2;
    acc3 += p * xj3;
  }

  // cross-group reduce (groups hold partials over different edges)
  acc0 += __shfl_xor(acc0, 16); acc0 += __shfl_xor(acc0, 32);
  acc1 += __shfl_xor(acc1, 16); acc1 += __shfl_xor(acc1, 32);
  acc2 += __shfl_xor(acc2, 16); acc2 += __shfl_xor(acc2, 32);
  acc3 += __shfl_xor(acc3, 16); acc3 += __shfl_xor(acc3, 32);
  lsum += __shfl_xor(lsum, 16); lsum += __shfl_xor(lsum, 32);

  if (g == 0) {
    float inv = 1.f / (lsum + 1e-16f);
    float4 bv = *(const float4*)&bias[4 * slot];
    float4 o;
    o.x = acc0 * inv + bv.x;
    o.y = acc1 * inv + bv.y;
    o.z = acc2 * inv + bv.z;
    o.w = acc3 * inv + bv.w;
    *(float4*)&out[(size_t)n * 64 + 4 * slot] = o;
  }
}

// ---------------- BN stage 1, C=256 ----------------
__global__ void bn_stage1_256_kernel(const float* __restrict__ x, float* __restrict__ partial) {
  int c = threadIdx.x;
  int r0 = blockIdx.x * 84;
  int r1 = min(r0 + 84, N_NODES);
  float s = 0.f, q = 0.f;
  for (int r = r0; r < r1; r++) {
    float v = x[(size_t)r * 256 + c];
    s += v;
    q += v * v;
  }
  partial[(size_t)blockIdx.x * 512 + c] = s;
  partial[(size_t)blockIdx.x * 512 + 256 + c] = q;
}

// ---------------- BN stage 1, C=64 ----------------
__global__ void bn_stage1_64_kernel(const float* __restrict__ x, float* __restrict__ partial) {
  __shared__ float ls[256], lq[256];
  int tid = threadIdx.x;
  int c = tid & 63, g = tid >> 6;
  int r0 = blockIdx.x * 84 + g;
  int r1 = min(blockIdx.x * 84 + 84, N_NODES);
  float s = 0.f, q = 0.f;
  for (int r = r0; r < r1; r += 4) {
    float v = x[(size_t)r * 64 + c];
    s += v;
    q += v * v;
  }
  ls[tid] = s;
  lq[tid] = q;
  __syncthreads();
  if (g == 0) {
    s += ls[64 + c] + ls[128 + c] + ls[192 + c];
    q += lq[64 + c] + lq[128 + c] + lq[192 + c];
    partial[(size_t)blockIdx.x * 128 + c] = s;
    partial[(size_t)blockIdx.x * 128 + 64 + c] = q;
  }
}

// ---------------- BN stage 2: finalize scale/shift ----------------
__global__ void bn_stage2_kernel(const float* __restrict__ partial, int C,
                                 const float* __restrict__ gamma, const float* __restrict__ beta,
                                 float* __restrict__ ss) {
  int c = threadIdx.x;
  if (c >= C) return;
  float s = 0.f, q = 0.f;
  for (int b = 0; b < 240; b++) {
    s += partial[(size_t)b * 2 * C + c];
    q += partial[(size_t)b * 2 * C + C + c];
  }
  float mu = s * (1.0f / N_NODES);
  float var = q * (1.0f / N_NODES) - mu * mu;
  float sc = gamma[c] * rsqrtf(var + BN_EPS);
  ss[c] = sc;
  ss[C + c] = beta[c] - mu * sc;
}

// ---------------- BN finalize + GELU, layer 1 -> bf16 ----------------
__global__ void bn_gelu1_kernel(const float* __restrict__ x, const float* __restrict__ ss,
                                unsigned short* __restrict__ y) {
  const int total4 = N_NODES * 256 / 4;
  for (int i = blockIdx.x * blockDim.x + threadIdx.x; i < total4;
       i += gridDim.x * blockDim.x) {
    int c0 = (i & 63) * 4;
    float4 v = ((const float4*)x)[i];
    float a0 = gelu_exact(v.x * ss[c0 + 0] + ss[256 + c0 + 0]);
    float a1 = gelu_exact(v.y * ss[c0 + 1] + ss[256 + c0 + 1]);
    float a2 = gelu_exact(v.z * ss[c0 + 2] + ss[256 + c0 + 2]);
    float a3 = gelu_exact(v.w * ss[c0 + 3] + ss[256 + c0 + 3]);
    ushort4v o = {f2bf(a0), f2bf(a1), f2bf(a2), f2bf(a3)};
    ((ushort4v*)y)[i] = o;
  }
}

// ---------------- BN finalize + GELU, layer 2 -> f32 (in place) ----------------
__global__ void bn_gelu2_kernel(const float* __restrict__ x, const float* __restrict__ ss,
                                float* __restrict__ y) {
  const int total4 = N_NODES * 64 / 4;
  for (int i = blockIdx.x * blockDim.x + threadIdx.x; i < total4;
       i += gridDim.x * blockDim.x) {
    int c0 = (i & 15) * 4;
    float4 v = ((const float4*)x)[i];
    float4 o;
    o.x = gelu_exact(v.x * ss[c0 + 0] + ss[64 + c0 + 0]);
    o.y = gelu_exact(v.y * ss[c0 + 1] + ss[64 + c0 + 1]);
    o.z = gelu_exact(v.z * ss[c0 + 2] + ss[64 + c0 + 2]);
    o.w = gelu_exact(v.w * ss[c0 + 3] + ss[64 + c0 + 3]);
    ((float4*)y)[i] = o;
  }
}

// ---------------- classifier head + log_softmax ----------------
__global__ void head_kernel(const float* __restrict__ h, const float* __restrict__ Wc,
                            const float* __restrict__ bc, float* __restrict__ out) {
  __shared__ float Ws[HID * OUTC];
  __shared__ float bs[OUTC];
  for (int i = threadIdx.x; i < HID * OUTC; i += 256) Ws[i] = Wc[i];
  for (int i = threadIdx.x; i < OUTC; i += 256) bs[i] = bc[i];
  __syncthreads();

  int wave = threadIdx.x >> 6;
  int lane = threadIdx.x & 63;
  int n = blockIdx.x * 4 + wave;
  if (n >= N_NODES) return;

  float hrow = h[(size_t)n * HID + lane];
  float dot = 0.f;
#pragma unroll
  for (int k = 0; k < HID; k++) {
    float hk = __shfl(hrow, k);
    if (lane < OUTC) dot += hk * Ws[k * OUTC + lane];
  }
  float z = (lane < OUTC) ? (dot + bs[lane]) : -INFINITY;
  float mv = z;
  for (int off = 32; off; off >>= 1) mv = fmaxf(mv, __shfl_xor(mv, off));
  float p = (lane < OUTC) ? expf(z - mv) : 0.f;
  float sum = p;
  for (int off = 32; off; off >>= 1) sum += __shfl_xor(sum, off);
  if (lane < OUTC) out[(size_t)n * OUTC + lane] = z - mv - logf(sum);
}

// ---------------- launch ----------------
extern "C" void kernel_launch(void* const* d_in, const int* in_sizes, int n_in,
                              void* d_out, int out_size, void* d_ws, size_t ws_size,
                              hipStream_t stream) {
  const float* x = (const float*)d_in[0];
  const int* eidx = (const int*)d_in[1];
  const float* W1l = (const float*)d_in[2];
  const float* W1r = (const float*)d_in[3];
  const float* att1 = (const float*)d_in[4];
  const float* b1 = (const float*)d_in[5];
  const float* bn1_g = (const float*)d_in[6];
  const float* bn1_b = (const float*)d_in[7];
  const float* W2l = (const float*)d_in[8];
  const float* W2r = (const float*)d_in[9];
  const float* att2 = (const float*)d_in[10];
  const float* b2 = (const float*)d_in[11];
  const float* bn2_g = (const float*)d_in[12];
  const float* bn2_b = (const float*)d_in[13];
  const float* Wc = (const float*)d_in[14];
  const float* bc = (const float*)d_in[15];
  float* out = (float*)d_out;

  const int* src = eidx;
  const int* dstv = eidx + N_EDGES;

  char* ws = (char*)d_ws;
  // Workspace map. agg1 reads C1full and writes out1 => DISJOINT regions now.
  // Time-disjoint reuse: out2 (f32, 5.12MB) over xb (bf16, 10.24MB; dead after GEMM1).
  unsigned short* C1full = (unsigned short*)(ws + 0);        // [20000][512] bf16, 20,480,000
  float* out1 = (float*)(ws + 20971520);                     // [20000][256] f32, 20,480,000
  unsigned short* out1b = (unsigned short*)(ws + 41943040);  // [20000][256] bf16, 10,240,000
  unsigned short* C2full = (unsigned short*)(ws + 52428800); // [20000][128] bf16, 5,120,000
  unsigned short* xb = (unsigned short*)(ws + 62914560);     // [20000][256] bf16, 10,240,000
  float* out2 = (float*)(ws + 62914560);                     // 5,120,000 (after xb dead)
  float* partial = (float*)(ws + 73400320);                  // 240*512 f32 = 491,520
  float* ss1 = (float*)(ws + 73891840);                      // 512 f32
  float* ss2 = (float*)(ws + 73893888);                      // 128 f32
  unsigned short* w1b = (unsigned short*)(ws + 73894400);    // 262,144
  unsigned short* w2b = (unsigned short*)(ws + 74156544);    // 65,536
  int* deg = (int*)(ws + 74222080);                          // 80,000
  int* cursor = (int*)(ws + 74302080);                       // 80,000 (contiguous)
  int* rowptr = (int*)(ws + 74382080);                       // 80,016
  int* csr_src = (int*)(ws + 74462096);                      // 1,280,000 -> ends 75,742,096

  hipMemsetAsync(deg, 0, 160000, stream);  // deg + cursor

  // casts
  cast_f32_bf16_kernel<<<5000, 256, 0, stream>>>(x, xb, 1280000);
  cast_weights_kernel<<<512, 256, 0, stream>>>(W1l, W1r, W2l, W2r, w1b, w2b);

  // layer-1 transform: one GEMM, N=512 ([xl | xr]), bf16 out
  gemm_bf16_kernel<<<dim3(8, 157), 256, 0, stream>>>(xb, w1b, C1full, N_NODES, 256, 512);

  // CSR build
  hist_kernel<<<(N_EDGES + 255) / 256, 256, 0, stream>>>(dstv, deg);
  scan_kernel<<<1, 1024, 0, stream>>>(deg, rowptr);
  scatter_kernel<<<(N_EDGES + 255) / 256, 256, 0, stream>>>(src, dstv, rowptr, cursor, csr_src);

  // layer-1 attention aggregation (+bias) -> out1 (f32); reads C1full directly
  agg1_kernel<<<N_NODES / 4, 256, 0, stream>>>(C1full, att1, b1, rowptr, csr_src, out1);

  // BN1 (two-stage, atomic-free) + GELU -> bf16
  bn_stage1_256_kernel<<<240, 256, 0, stream>>>(out1, partial);
  bn_stage2_kernel<<<1, 256, 0, stream>>>(partial, 256, bn1_g, bn1_b, ss1);
  bn_gelu1_kernel<<<2048, 256, 0, stream>>>(out1, ss1, out1b);

  // layer-2 transform: one GEMM, N=128 ([xl2 | xr2]), bf16 out
  gemm_bf16_kernel<<<dim3(2, 157), 256, 0, stream>>>(out1b, w2b, C2full, N_NODES, 256, 128);

  // layer-2 attention aggregation (+bias)
  agg2_kernel<<<N_NODES / 4, 256, 0, stream>>>(C2full, att2, b2, rowptr, csr_src, out2);

  // BN2 + GELU (in place)
  bn_stage1_64_kernel<<<240, 256, 0, stream>>>(out2, partial);
  bn_stage2_kernel<<<1, 64, 0, stream>>>(partial, 64, bn2_g, bn2_b, ss2);
  bn_gelu2_kernel<<<1280, 256, 0, stream>>>(out2, ss2, out2);

  // classifier + log_softmax
  head_kernel<<<N_NODES / 4, 256, 0, stream>>>(out2, Wc, bc, out);
}